// Round 8
// baseline (190.275 us; speedup 1.0000x reference)
//
#include <hip/hip_runtime.h>
#include <math.h>

#define N_PTS 4096
#define BATCH 4
#define JS 8                  // j-split factor
#define JCH (N_PTS / JS)      // 512 points per j-chunk

typedef short bf16x8 __attribute__((ext_vector_type(8)));
typedef short bf16x4 __attribute__((ext_vector_type(4)));
typedef float f32x4 __attribute__((ext_vector_type(4)));
typedef _Float16 f16x8 __attribute__((ext_vector_type(8)));

// f32 -> fp16 (RNE), bit pattern in short
__device__ inline short f2h(float f) {
    _Float16 h = (_Float16)f;
    return __builtin_bit_cast(short, h);
}

// ---------------------------------------------------------------------------
// maxd2 init
// ---------------------------------------------------------------------------
__global__ void init_maxd2_kernel(unsigned int* p) {
    if (threadIdx.x < BATCH) p[threadIdx.x] = 0u;
}

// ---------------------------------------------------------------------------
// Per-batch max pairwise squared distance. Grid: (N/64, JS, B), 256 threads.
// ---------------------------------------------------------------------------
__global__ __launch_bounds__(256) void radius_max_kernel(
    const float* __restrict__ xyz, unsigned int* __restrict__ maxd2)
{
    const int b = blockIdx.z;
    __shared__ float4 sj[JCH];
    const float* xb = xyz + (size_t)b * N_PTS * 3;
    const int j0 = blockIdx.y * JCH;
    for (int idx = threadIdx.x; idx < JCH; idx += 256) {
        int j = j0 + idx;
        sj[idx] = make_float4(xb[j*3+0], xb[j*3+1], xb[j*3+2], 0.f);
    }
    __syncthreads();
    const int il = threadIdx.x & 63;
    const int jq = threadIdx.x >> 6;
    const int i = blockIdx.x * 64 + il;
    const float xi = xb[i*3+0], yi = xb[i*3+1], zi = xb[i*3+2];
    float m = 0.f;
    const int jb = jq * (JCH / 4);
    #pragma unroll 4
    for (int j = jb; j < jb + JCH / 4; ++j) {
        float4 p = sj[j];
        float dx = xi - p.x, dy = yi - p.y, dz = zi - p.z;
        m = fmaxf(m, dx * dx + dy * dy + dz * dz);
    }
    for (int off = 32; off >= 1; off >>= 1) m = fmaxf(m, __shfl_down(m, off));
    __shared__ float wred[4];
    if ((threadIdx.x & 63) == 0) wred[threadIdx.x >> 6] = m;
    __syncthreads();
    if (threadIdx.x == 0) {
        float mm = fmaxf(fmaxf(wred[0], wred[1]), fmaxf(wred[2], wred[3]));
        atomicMax(&maxd2[b], __float_as_uint(mm));
    }
}

// ---------------------------------------------------------------------------
// Eigen accumulate, BRANCHLESS: per-(i, j-chunk) partial (cnt,S1,S2).
// sj.w = |xj|^2; d2 = x2i + p.w - 2*dot via explicit fmaf (exact 0 for j==i,
// same op order as staging => self surely included, subtracted in finalize).
// wf in {0,1}: acc += wf * feat  (6 fmaf + 3 mul + 4 add, no divergence).
// Grid: (N/64, JS, B), 256 threads.
// ---------------------------------------------------------------------------
__global__ __launch_bounds__(256) void eigen_accum_kernel(
    const float* __restrict__ xyz, const unsigned int* __restrict__ maxd2,
    float* __restrict__ pbuf)
{
    const int b = blockIdx.z, js = blockIdx.y;
    __shared__ float4 sj[JCH];
    __shared__ float red[4][64][10];
    const float* xb = xyz + (size_t)b * N_PTS * 3;
    const int j0 = js * JCH;
    for (int idx = threadIdx.x; idx < JCH; idx += 256) {
        int j = j0 + idx;
        float x = xb[j*3+0], y = xb[j*3+1], z = xb[j*3+2];
        sj[idx] = make_float4(x, y, z, fmaf(x, x, fmaf(y, y, z * z)));
    }
    __syncthreads();
    const int il = threadIdx.x & 63;
    const int jq = threadIdx.x >> 6;
    const int i = blockIdx.x * 64 + il;
    const float xi = xb[i*3+0], yi = xb[i*3+1], zi = xb[i*3+2];
    const float x2i = fmaf(xi, xi, fmaf(yi, yi, zi * zi));
    const float r2 = 0.01f * __uint_as_float(maxd2[b]);   // (0.1*maxd)^2

    float acc[10] = {0.f,0.f,0.f,0.f,0.f,0.f,0.f,0.f,0.f,0.f};
    const int jb = jq * (JCH / 4);
    for (int j = jb; j < jb + JCH / 4; ++j) {
        float4 p = sj[j];
        float dot = fmaf(xi, p.x, fmaf(yi, p.y, zi * p.z));
        float d2 = fmaf(-2.f, dot, x2i + p.w);
        float wf = (d2 < r2) ? 1.f : 0.f;
        float wx = wf * p.x, wy = wf * p.y, wz = wf * p.z;
        acc[0] += wf;
        acc[1] += wx;  acc[2] += wy;  acc[3] += wz;
        acc[4] = fmaf(wx, p.x, acc[4]);
        acc[5] = fmaf(wx, p.y, acc[5]);
        acc[6] = fmaf(wx, p.z, acc[6]);
        acc[7] = fmaf(wy, p.y, acc[7]);
        acc[8] = fmaf(wy, p.z, acc[8]);
        acc[9] = fmaf(wz, p.z, acc[9]);
    }
    #pragma unroll
    for (int q = 0; q < 10; ++q) red[jq][il][q] = acc[q];
    __syncthreads();
    if (threadIdx.x < 64) {
        float* dst = pbuf + ((size_t)(b * JS + js) * N_PTS + i) * 10;
        #pragma unroll
        for (int q = 0; q < 10; ++q)
            dst[q] = red[0][il][q] + red[1][il][q] + red[2][il][q] + red[3][il][q];
    }
}

// ---------------------------------------------------------------------------
// Eigen finalize -> fp16 zinT[b][n][160..163]  (zinT: [B][N][192])
// ---------------------------------------------------------------------------
__global__ __launch_bounds__(256) void eigen_finalize_kernel(
    const float* __restrict__ xyz, const float* __restrict__ pbuf,
    const float* __restrict__ ew1, const float* __restrict__ eb1,
    const float* __restrict__ ew2, const float* __restrict__ eb2,
    short* __restrict__ zinT)
{
    int id = blockIdx.x * 256 + threadIdx.x;
    if (id >= BATCH * N_PTS) return;
    int b = id >> 12, i = id & (N_PTS - 1);

    double s[10] = {0,0,0,0,0,0,0,0,0,0};
    for (int js = 0; js < JS; ++js) {
        const float* src = pbuf + ((size_t)(b * JS + js) * N_PTS + i) * 10;
        #pragma unroll
        for (int q = 0; q < 10; ++q) s[q] += (double)src[q];
    }
    const float* xb = xyz + (size_t)b * N_PTS * 3;
    float xi = xb[i*3+0], yi = xb[i*3+1], zi = xb[i*3+2];
    s[0] -= 1.0;
    s[1] -= (double)xi;        s[2] -= (double)yi;        s[3] -= (double)zi;
    s[4] -= (double)(xi * xi); s[5] -= (double)(xi * yi); s[6] -= (double)(xi * zi);
    s[7] -= (double)(yi * yi); s[8] -= (double)(yi * zi); s[9] -= (double)(zi * zi);

    double cnt = s[0];
    double denom = fmax(cnt, 1.0);
    double mx = s[1] / denom, my = s[2] / denom, mz = s[3] / denom;
    const double invN = 1.0 / (double)N_PTS;
    double c00 = (s[4] - cnt * mx * mx) * invN;
    double c01 = (s[5] - cnt * mx * my) * invN;
    double c02 = (s[6] - cnt * mx * mz) * invN;
    double c11 = (s[7] - cnt * my * my) * invN;
    double c12 = (s[8] - cnt * my * mz) * invN;
    double c22 = (s[9] - cnt * mz * mz) * invN;

    double qm = (c00 + c11 + c22) / 3.0;
    double p1 = c01*c01 + c02*c02 + c12*c12;
    double a0 = c00 - qm, a1 = c11 - qm, a2 = c22 - qm;
    double p2 = a0*a0 + a1*a1 + a2*a2 + 2.0*p1;
    double e_lo, e_mid, e_hi;
    if (p2 < 1e-32) {
        e_lo = e_mid = e_hi = qm;
    } else {
        double p = sqrt(p2 / 6.0);
        double inv = 1.0 / p;
        double b00 = a0*inv, b11 = a1*inv, b22 = a2*inv;
        double b01 = c01*inv, b02 = c02*inv, b12 = c12*inv;
        double detB = b00*(b11*b22 - b12*b12)
                    - b01*(b01*b22 - b12*b02)
                    + b02*(b01*b12 - b11*b02);
        double r = 0.5 * detB;
        r = fmin(1.0, fmax(-1.0, r));
        double phi = acos(r) / 3.0;
        double two_p = 2.0 * p;
        e_hi = qm + two_p * cos(phi);
        e_lo = qm + two_p * cos(phi + 2.0943951023931953);
        e_mid = 3.0 * qm - e_hi - e_lo;
    }
    float e0 = (float)e_lo, e1 = (float)e_mid, e2 = (float)e_hi;

    float t[4];
    #pragma unroll
    for (int o = 0; o < 4; ++o)
        t[o] = fmaxf(e0 * ew1[o*3+0] + e1 * ew1[o*3+1] +
                     e2 * ew1[o*3+2] + eb1[o], 0.f);
    bf16x4 ov;
    #pragma unroll
    for (int o = 0; o < 4; ++o) {
        float h = t[0]*ew2[o*4+0] + t[1]*ew2[o*4+1] +
                  t[2]*ew2[o*4+2] + t[3]*ew2[o*4+3] + eb2[o];
        ov[o] = f2h(h);
    }
    *(bf16x4*)&zinT[((size_t)b * N_PTS + i) * 192 + 160] = ov;
}

// ---------------------------------------------------------------------------
// h1 [B][128][N] f32 -> zinT [B][N][192] fp16 ch 0..127, zero ch 164..191.
// ---------------------------------------------------------------------------
__global__ __launch_bounds__(256) void h1_transpose_kernel(
    const float* __restrict__ h1, short* __restrict__ zinT)
{
    const int b = blockIdx.y;
    const int n0 = blockIdx.x * 32;
    __shared__ float tile[128][33];
    #pragma unroll
    for (int it = 0; it < 16; ++it) {
        int idx = it * 256 + threadIdx.x;
        int c = idx >> 5, n = idx & 31;
        tile[c][n] = h1[((size_t)b * 128 + c) * N_PTS + n0 + n];
    }
    __syncthreads();
    #pragma unroll
    for (int it = 0; it < 16; ++it) {
        int idx = it * 256 + threadIdx.x;
        int c = idx & 127, n = idx >> 7;
        zinT[((size_t)b * N_PTS + n0 + n) * 192 + c] = f2h(tile[c][n]);
    }
    for (int idx = threadIdx.x; idx < 32 * 28; idx += 256) {
        int n = idx / 28, c = 164 + idx % 28;
        zinT[((size_t)b * N_PTS + n0 + n) * 192 + c] = 0;
    }
}

// ---------------------------------------------------------------------------
// h2_in [B][1024][N] f32 -> t_h2 [B][N][1024] fp16. Grid: (N/32, 8, B).
// ---------------------------------------------------------------------------
__global__ __launch_bounds__(256) void h2_transpose_kernel(
    const float* __restrict__ h2, short* __restrict__ t_h2)
{
    const int b = blockIdx.z;
    const int c0 = blockIdx.y * 128;
    const int n0 = blockIdx.x * 32;
    __shared__ float tile[128][33];
    #pragma unroll
    for (int it = 0; it < 16; ++it) {
        int idx = it * 256 + threadIdx.x;
        int c = idx >> 5, n = idx & 31;
        tile[c][n] = h2[((size_t)b * 1024 + c0 + c) * N_PTS + n0 + n];
    }
    __syncthreads();
    #pragma unroll
    for (int it = 0; it < 16; ++it) {
        int idx = it * 256 + threadIdx.x;
        int c = idx & 127, n = idx >> 7;
        t_h2[((size_t)b * N_PTS + n0 + n) * 1024 + c0 + c] = f2h(tile[c][n]);
    }
}

// ---------------------------------------------------------------------------
// xyz passthrough (f32)
// ---------------------------------------------------------------------------
__global__ __launch_bounds__(256) void xyz_out_kernel(
    const float* __restrict__ xyz, float* __restrict__ out)
{
    int idx = blockIdx.x * 256 + threadIdx.x;
    if (idx < BATCH * N_PTS * 3) out[idx] = xyz[idx];
}

// ---------------------------------------------------------------------------
// Weight f32 -> fp16, k-linear, zero-padded to [Mp][Kp]
// ---------------------------------------------------------------------------
__global__ __launch_bounds__(256) void conv_weight_kernel(
    const float* __restrict__ W, short* __restrict__ Wb,
    int M, int K, int Mp, int Kp)
{
    int id = blockIdx.x * 256 + threadIdx.x;
    if (id >= Mp * Kp) return;
    int mrow = id / Kp, k = id - mrow * Kp;
    float v = (mrow < M && k < K) ? W[(size_t)mrow * K + k] : 0.f;
    Wb[(size_t)mrow * Kp + k] = f2h(v);
}

// ---------------------------------------------------------------------------
// fp16 MFMA GEMM, k-contiguous X (XT: [B][N][Kp] fp16). See round-7 notes.
// ---------------------------------------------------------------------------
template<int BM, int BN, bool OUTT>
__global__ __launch_bounds__(256) void mfma_gemm(
    const short* __restrict__ Wb, const short* __restrict__ XT,
    const float* __restrict__ bias, const float* __restrict__ scale,
    const float* __restrict__ shift, void* __restrict__ Yv,
    int M, int Kp, int ostride, size_t ybs)
{
    constexpr int LDW = 40;                    // padded LDS stride (shorts)
    constexpr int FM = BM / 32, FN = BN / 32;  // frags per wave
    constexpr int NCH = (BM + BN) * 4;         // 16B chunks per K-step
    constexpr int NREG = (NCH + 255) / 256;
    __shared__ __align__(16) short Wl[2][BM][LDW];
    __shared__ __align__(16) short Xl[2][BN][LDW];

    const int tid = threadIdx.x;
    const int lane = tid & 63, wave = tid >> 6;
    const int g = lane >> 4, r = lane & 15;
    const int wr = wave >> 1, wc = wave & 1;
    const int wm0 = wr * (BM / 2), wn0 = wc * (BN / 2);
    const int b = blockIdx.z;
    const int m0 = blockIdx.y * BM, n0 = blockIdx.x * BN;
    const int NT = Kp >> 5;

    f32x4 acc[FM][FN];
    #pragma unroll
    for (int i = 0; i < FM; ++i)
        #pragma unroll
        for (int jj = 0; jj < FN; ++jj)
            acc[i][jj] = (f32x4){0.f, 0.f, 0.f, 0.f};

    bf16x8 rg[NREG];

    auto load_regs = [&](int t) {
        #pragma unroll
        for (int u = 0; u < NREG; ++u) {
            int id = u * 256 + tid;
            if (id < NCH) {
                if (id < BM * 4) {
                    int m = id >> 2, c4 = id & 3;
                    rg[u] = *(const bf16x8*)&Wb[(size_t)(m0 + m) * Kp + (t << 5) + c4 * 8];
                } else {
                    int id2 = id - BM * 4;
                    int n = id2 >> 2, c4 = id2 & 3;
                    rg[u] = *(const bf16x8*)&XT[((size_t)b * N_PTS + n0 + n) * Kp + (t << 5) + c4 * 8];
                }
            }
        }
    };
    auto write_lds = [&](int nb) {
        #pragma unroll
        for (int u = 0; u < NREG; ++u) {
            int id = u * 256 + tid;
            if (id < NCH) {
                if (id < BM * 4) {
                    int m = id >> 2, c4 = id & 3;
                    *(bf16x8*)&Wl[nb][m][c4 * 8] = rg[u];
                } else {
                    int id2 = id - BM * 4;
                    int n = id2 >> 2, c4 = id2 & 3;
                    *(bf16x8*)&Xl[nb][n][c4 * 8] = rg[u];
                }
            }
        }
    };
    auto compute = [&](int cb) {
        #pragma unroll
        for (int fn = 0; fn < FN; ++fn) {
            bf16x8 bb = *(const bf16x8*)&Xl[cb][wn0 + fn * 16 + r][g * 8];
            #pragma unroll
            for (int fm = 0; fm < FM; ++fm) {
                bf16x8 a = *(const bf16x8*)&Wl[cb][wm0 + fm * 16 + r][g * 8];
                acc[fm][fn] = __builtin_amdgcn_mfma_f32_16x16x32_f16(
                    __builtin_bit_cast(f16x8, a),
                    __builtin_bit_cast(f16x8, bb),
                    acc[fm][fn], 0, 0, 0);
            }
        }
    };

    load_regs(0);
    write_lds(0);
    __syncthreads();
    for (int t = 0; t < NT; ++t) {
        int cb = t & 1;
        if (t + 1 < NT) load_regs(t + 1);
        compute(cb);
        if (t + 1 < NT) write_lds(cb ^ 1);
        __syncthreads();
    }

    if constexpr (OUTT) {
        short* Y = (short*)Yv;
        #pragma unroll
        for (int fm = 0; fm < FM; ++fm) {
            int mb = m0 + wm0 + fm * 16 + g * 4;
            if (mb < M) {
                float4 b4 = *(const float4*)&bias[mb];
                float4 s4 = *(const float4*)&scale[mb];
                float4 h4 = *(const float4*)&shift[mb];
                #pragma unroll
                for (int fn = 0; fn < FN; ++fn) {
                    int n = n0 + wn0 + fn * 16 + r;
                    f32x4 a = acc[fm][fn];
                    bf16x4 o;
                    o[0] = f2h(fmaxf(fmaf(a[0] + b4.x, s4.x, h4.x), 0.f));
                    o[1] = f2h(fmaxf(fmaf(a[1] + b4.y, s4.y, h4.y), 0.f));
                    o[2] = f2h(fmaxf(fmaf(a[2] + b4.z, s4.z, h4.z), 0.f));
                    o[3] = f2h(fmaxf(fmaf(a[3] + b4.w, s4.w, h4.w), 0.f));
                    *(bf16x4*)&Y[((size_t)b * N_PTS + n) * ostride + mb] = o;
                }
            }
        }
    } else {
        float* Y = (float*)Yv;
        #pragma unroll
        for (int fm = 0; fm < FM; ++fm) {
            int mbase = m0 + wm0 + fm * 16 + g * 4;
            #pragma unroll
            for (int e = 0; e < 4; ++e) {
                int mm = mbase + e;
                if (mm >= M) continue;
                float bs = bias[mm], sc = scale[mm], sh = shift[mm];
                #pragma unroll
                for (int fn = 0; fn < FN; ++fn) {
                    int n = n0 + wn0 + fn * 16 + r;
                    float v = fmaxf(fmaf(acc[fm][fn][e] + bs, sc, sh), 0.f);
                    Y[(size_t)b * ybs + (size_t)mm * N_PTS + n] = v;
                }
            }
        }
    }
}

// ---------------------------------------------------------------------------
extern "C" void kernel_launch(void* const* d_in, const int* in_sizes, int n_in,
                              void* d_out, int out_size, void* d_ws, size_t ws_size,
                              hipStream_t stream)
{
    const float* xyz   = (const float*)d_in[0];
    const float* h1    = (const float*)d_in[1];
    const float* h2_in = (const float*)d_in[2];
    const float* dg_w1 = (const float*)d_in[3];
    const float* dg_b1 = (const float*)d_in[4];
    const float* dg_s1 = (const float*)d_in[5];
    const float* dg_t1 = (const float*)d_in[6];
    const float* dg_w2 = (const float*)d_in[7];
    const float* dg_b2 = (const float*)d_in[8];
    const float* dg_s2 = (const float*)d_in[9];
    const float* dg_t2 = (const float*)d_in[10];
    const float* dg_w3 = (const float*)d_in[11];
    const float* dg_b3 = (const float*)d_in[12];
    const float* dg_s3 = (const float*)d_in[13];
    const float* dg_t3 = (const float*)d_in[14];
    const float* ed_w1 = (const float*)d_in[15];
    const float* ed_b1 = (const float*)d_in[16];
    const float* ed_w2 = (const float*)d_in[17];
    const float* ed_b2 = (const float*)d_in[18];
    const float* w1 = (const float*)d_in[19];
    const float* b1 = (const float*)d_in[20];
    const float* s1 = (const float*)d_in[21];
    const float* t1 = (const float*)d_in[22];
    const float* w2 = (const float*)d_in[23];
    const float* b2 = (const float*)d_in[24];
    const float* s2 = (const float*)d_in[25];
    const float* t2 = (const float*)d_in[26];
    const float* w3 = (const float*)d_in[27];
    const float* b3 = (const float*)d_in[28];
    const float* s3 = (const float*)d_in[29];
    const float* t3 = (const float*)d_in[30];

    float* out = (float*)d_out;

    // workspace layout (bufB aliases t_h2, bufD aliases bufA)
    char* ws = (char*)d_ws;
    size_t off = 0;
    auto alloc = [&](size_t bytes) {
        char* p = ws + off;
        off += (bytes + 255) & ~(size_t)255;
        return p;
    };
    unsigned int* maxd2 = (unsigned int*)alloc(256);
    short* wb1  = (short*)alloc((size_t)256 * 1024 * 2);
    short* wb2  = (short*)alloc((size_t)64  * 256  * 2);
    short* wb3  = (short*)alloc((size_t)64  * 64   * 2);
    short* wbf1 = (short*)alloc((size_t)512 * 192  * 2);
    short* wbf2 = (short*)alloc((size_t)256 * 512  * 2);
    short* wbf3 = (short*)alloc((size_t)128 * 256  * 2);
    short* zinT = (short*)alloc((size_t)BATCH * N_PTS * 192 * 2);   // 6.3 MB
    short* t_h2 = (short*)alloc((size_t)BATCH * N_PTS * 1024 * 2);  // 33.5 MB
    short* bufA = (short*)alloc((size_t)BATCH * N_PTS * 256 * 2);   // 8.4 MB
    short* bufC = (short*)alloc((size_t)BATCH * N_PTS * 64 * 2);    // 2.1 MB
    float* pbuf = (float*)alloc((size_t)BATCH * JS * N_PTS * 10 * 4); // 5.2 MB
    short* bufB = t_h2;   // [B][N][512] fp16 (t_h2 dead after DG1)
    short* bufD = bufA;   // [B][N][256] fp16 (bufA dead after DG2)

    init_maxd2_kernel<<<1, 64, 0, stream>>>(maxd2);

    auto wconv = [&](const float* W, short* Wb, int M, int K, int Mp, int Kp) {
        conv_weight_kernel<<<(Mp * Kp + 255) / 256, 256, 0, stream>>>(W, Wb, M, K, Mp, Kp);
    };
    wconv(dg_w1, wb1, 256, 1024, 256, 1024);
    wconv(dg_w2, wb2, 64, 256, 64, 256);
    wconv(dg_w3, wb3, 32, 64, 64, 64);
    wconv(w1, wbf1, 512, 164, 512, 192);
    wconv(w2, wbf2, 256, 512, 256, 512);
    wconv(w3, wbf3, 128, 256, 128, 256);

    // eigen branch
    dim3 gsplit(N_PTS / 64, JS, BATCH);
    radius_max_kernel<<<gsplit, 256, 0, stream>>>(xyz, maxd2);
    eigen_accum_kernel<<<gsplit, 256, 0, stream>>>(xyz, maxd2, pbuf);
    eigen_finalize_kernel<<<(BATCH * N_PTS + 255) / 256, 256, 0, stream>>>(
        xyz, pbuf, ed_w1, ed_b1, ed_w2, ed_b2, zinT);

    // layout transposes
    h2_transpose_kernel<<<dim3(N_PTS / 32, 8, BATCH), 256, 0, stream>>>(h2_in, t_h2);
    h1_transpose_kernel<<<dim3(N_PTS / 32, BATCH), 256, 0, stream>>>(h1, zinT);
    xyz_out_kernel<<<(BATCH * N_PTS * 3 + 255) / 256, 256, 0, stream>>>(xyz, out);

    // GEMM chain (all X k-contiguous); grids sized for >=4 blocks/CU
    // DG1: 1024 -> 256
    mfma_gemm<64, 64, true><<<dim3(N_PTS/64, 4, BATCH), 256, 0, stream>>>(
        wb1, t_h2, dg_b1, dg_s1, dg_t1, bufA, 256, 1024, 256, 0);
    // DG2: 256 -> 64
    mfma_gemm<64, 32, true><<<dim3(N_PTS/32, 1, BATCH), 256, 0, stream>>>(
        wb2, bufA, dg_b2, dg_s2, dg_t2, bufC, 64, 256, 64, 0);
    // DG3: 64 -> 32 (zinT ch 128..159)
    mfma_gemm<64, 32, true><<<dim3(N_PTS/32, 1, BATCH), 256, 0, stream>>>(
        wb3, bufC, dg_b3, dg_s3, dg_t3, zinT + 128, 32, 64, 192, 0);
    // F1: 192 -> 512
    mfma_gemm<128, 64, true><<<dim3(N_PTS/64, 4, BATCH), 256, 0, stream>>>(
        wbf1, zinT, b1, s1, t1, bufB, 512, 192, 512, 0);
    // F2: 512 -> 256
    mfma_gemm<64, 64, true><<<dim3(N_PTS/64, 4, BATCH), 256, 0, stream>>>(
        wbf2, bufB, b2, s2, t2, bufD, 256, 512, 256, 0);
    // F3: 256 -> 128 (f32 [b][m][n] into d_out after xyz)
    mfma_gemm<64, 32, false><<<dim3(N_PTS/32, 2, BATCH), 256, 0, stream>>>(
        wbf3, bufD, b3, s3, t3, out + (size_t)BATCH * N_PTS * 3, 128, 256, 0,
        (size_t)128 * N_PTS);
}

// Round 9
// 159.290 us; speedup vs baseline: 1.1945x; 1.1945x over previous
//
#include <hip/hip_runtime.h>
#include <math.h>

#define N_PTS 4096
#define BATCH 4
#define JS 8                  // j-split factor
#define JCH (N_PTS / JS)      // 512 points per j-chunk

typedef short bf16x8 __attribute__((ext_vector_type(8)));
typedef short bf16x4 __attribute__((ext_vector_type(4)));
typedef float f32x4 __attribute__((ext_vector_type(4)));
typedef _Float16 f16x8 __attribute__((ext_vector_type(8)));

// f32 -> fp16 (RNE), bit pattern in short
__device__ inline short f2h(float f) {
    _Float16 h = (_Float16)f;
    return __builtin_bit_cast(short, h);
}

// ---------------------------------------------------------------------------
// maxd2 init
// ---------------------------------------------------------------------------
__global__ void init_maxd2_kernel(unsigned int* p) {
    if (threadIdx.x < BATCH) p[threadIdx.x] = 0u;
}

// ---------------------------------------------------------------------------
// Per-batch max pairwise squared distance. Grid: (N/64, JS, B), 256 threads.
// dot-form d2 (6 VALU/pair incl. max); LDS float4 broadcast reads.
// ---------------------------------------------------------------------------
__global__ __launch_bounds__(256) void radius_max_kernel(
    const float* __restrict__ xyz, unsigned int* __restrict__ maxd2)
{
    const int b = blockIdx.z;
    __shared__ float4 sj[JCH];
    const float* xb = xyz + (size_t)b * N_PTS * 3;
    const int j0 = blockIdx.y * JCH;
    for (int idx = threadIdx.x; idx < JCH; idx += 256) {
        int j = j0 + idx;
        float x = xb[j*3+0], y = xb[j*3+1], z = xb[j*3+2];
        sj[idx] = make_float4(x, y, z, fmaf(x, x, fmaf(y, y, z * z)));
    }
    __syncthreads();
    const int il = threadIdx.x & 63;
    const int jq = threadIdx.x >> 6;
    const int i = blockIdx.x * 64 + il;
    const float xi = xb[i*3+0], yi = xb[i*3+1], zi = xb[i*3+2];
    const float x2i = fmaf(xi, xi, fmaf(yi, yi, zi * zi));
    float m = 0.f;
    const int jb = jq * (JCH / 4);
    #pragma unroll 4
    for (int j = jb; j < jb + JCH / 4; ++j) {
        float4 p = sj[j];
        float dot = fmaf(xi, p.x, fmaf(yi, p.y, zi * p.z));
        float d2 = fmaf(-2.f, dot, x2i + p.w);
        m = fmaxf(m, d2);
    }
    for (int off = 32; off >= 1; off >>= 1) m = fmaxf(m, __shfl_down(m, off));
    __shared__ float wred[4];
    if ((threadIdx.x & 63) == 0) wred[threadIdx.x >> 6] = m;
    __syncthreads();
    if (threadIdx.x == 0) {
        float mm = fmaxf(fmaxf(wred[0], wred[1]), fmaxf(wred[2], wred[3]));
        atomicMax(&maxd2[b], __float_as_uint(mm));
    }
}

// ---------------------------------------------------------------------------
// Eigen accumulate via MFMA:  ACC[i][q] = sum_j WF[i][j] * F[j][q]
// Per block: 64 i x 512 j. Per wave: 16-i tile, full 512 j in 16 slices of 32.
// A-fragment (WF 16x32, 0/1) computed IN REGISTERS: lane (r,g) slot s holds
// wf(i0w+r, j0+g*8+s). B-fragment read from F_T[16][512] fp16 with the
// IDENTICAL slot->k labeling (lane (r,g) reads F_T[r][j0+g*8..+7]) -- the
// same A/B slot symmetry validated by the working GEMM (rounds 5-8).
// Distance test in f32 (self term exactly 0 by identical fmaf ordering,
// subtracted in finalize with fp16-quantized values for exact cancellation).
// D layout: lane (r,g) reg e -> ACC[i = g*4+e][q = r]  [m89/m91].
// pbuf[b][js][i][16] f32.  Grid: (N/64, JS, B), 256 threads.
// ---------------------------------------------------------------------------
__global__ __launch_bounds__(256) void eigen_accum_kernel(
    const float* __restrict__ xyz, const unsigned int* __restrict__ maxd2,
    float* __restrict__ pbuf)
{
    const int b = blockIdx.z, js = blockIdx.y;
    __shared__ __align__(16) float4 sj4[JCH];                 // 8 KB
    __shared__ __align__(16) _Float16 Ft[16][JCH + 8];        // 16.25 KB
    const float* xb = xyz + (size_t)b * N_PTS * 3;
    const int j0g = js * JCH;
    for (int idx = threadIdx.x; idx < JCH; idx += 256) {
        int j = j0g + idx;
        float x = xb[j*3+0], y = xb[j*3+1], z = xb[j*3+2];
        sj4[idx] = make_float4(x, y, z, fmaf(x, x, fmaf(y, y, z * z)));
        Ft[0][idx] = (_Float16)1.f;
        Ft[1][idx] = (_Float16)x;
        Ft[2][idx] = (_Float16)y;
        Ft[3][idx] = (_Float16)z;
        Ft[4][idx] = (_Float16)(x * x);
        Ft[5][idx] = (_Float16)(x * y);
        Ft[6][idx] = (_Float16)(x * z);
        Ft[7][idx] = (_Float16)(y * y);
        Ft[8][idx] = (_Float16)(y * z);
        Ft[9][idx] = (_Float16)(z * z);
        Ft[10][idx] = (_Float16)0.f; Ft[11][idx] = (_Float16)0.f;
        Ft[12][idx] = (_Float16)0.f; Ft[13][idx] = (_Float16)0.f;
        Ft[14][idx] = (_Float16)0.f; Ft[15][idx] = (_Float16)0.f;
    }
    __syncthreads();

    const int lane = threadIdx.x & 63, wave = threadIdx.x >> 6;
    const int r = lane & 15, g = lane >> 4;
    const int i_wf = blockIdx.x * 64 + wave * 16 + r;   // A-side row of this lane
    const float xi = xb[i_wf*3+0], yi = xb[i_wf*3+1], zi = xb[i_wf*3+2];
    const float x2i = fmaf(xi, xi, fmaf(yi, yi, zi * zi));
    const float r2 = 0.01f * __uint_as_float(maxd2[b]);  // (0.1*maxd)^2

    f32x4 acc = (f32x4){0.f, 0.f, 0.f, 0.f};
    #pragma unroll 4
    for (int t = 0; t < JCH / 32; ++t) {
        const int jb = t * 32 + g * 8;
        f16x8 wfv;
        #pragma unroll
        for (int s = 0; s < 8; ++s) {
            float4 p = sj4[jb + s];
            float dot = fmaf(xi, p.x, fmaf(yi, p.y, zi * p.z));
            float d2 = fmaf(-2.f, dot, x2i + p.w);
            wfv[s] = (d2 < r2) ? (_Float16)1.f : (_Float16)0.f;
        }
        f16x8 fv = *(const f16x8*)&Ft[r][jb];
        acc = __builtin_amdgcn_mfma_f32_16x16x32_f16(wfv, fv, acc, 0, 0, 0);
    }

    // lane (r,g) reg e holds ACC[i = i0 + wave*16 + g*4 + e][q = r]
    const int i_out = blockIdx.x * 64 + wave * 16 + g * 4;
    float* dst = pbuf + ((size_t)(b * JS + js) * N_PTS + i_out) * 16 + r;
    #pragma unroll
    for (int e = 0; e < 4; ++e) dst[(size_t)e * 16] = acc[e];
}

// ---------------------------------------------------------------------------
// Eigen finalize: sum JS partials (double), subtract QUANTIZED self terms,
// Cardano eigvalsh, ED MLP -> fp16 zinT ch 160..163. Also copies xyz -> out.
// One thread per point. pbuf stride 16.
// ---------------------------------------------------------------------------
__global__ __launch_bounds__(256) void eigen_finalize_kernel(
    const float* __restrict__ xyz, const float* __restrict__ pbuf,
    const float* __restrict__ ew1, const float* __restrict__ eb1,
    const float* __restrict__ ew2, const float* __restrict__ eb2,
    short* __restrict__ zinT, float* __restrict__ out)
{
    int id = blockIdx.x * 256 + threadIdx.x;
    if (id >= BATCH * N_PTS) return;
    int b = id >> 12, i = id & (N_PTS - 1);

    // xyz passthrough
    out[id*3+0] = xyz[id*3+0];
    out[id*3+1] = xyz[id*3+1];
    out[id*3+2] = xyz[id*3+2];

    double s[10] = {0,0,0,0,0,0,0,0,0,0};
    for (int js = 0; js < JS; ++js) {
        const float* src = pbuf + ((size_t)(b * JS + js) * N_PTS + i) * 16;
        #pragma unroll
        for (int q = 0; q < 10; ++q) s[q] += (double)src[q];
    }
    // subtract self contribution (fp16-quantized, matching the Ft staging)
    const float* xb = xyz + (size_t)b * N_PTS * 3;
    float xi = xb[i*3+0], yi = xb[i*3+1], zi = xb[i*3+2];
    s[0] -= 1.0;
    s[1] -= (double)(float)(_Float16)xi;
    s[2] -= (double)(float)(_Float16)yi;
    s[3] -= (double)(float)(_Float16)zi;
    s[4] -= (double)(float)(_Float16)(xi * xi);
    s[5] -= (double)(float)(_Float16)(xi * yi);
    s[6] -= (double)(float)(_Float16)(xi * zi);
    s[7] -= (double)(float)(_Float16)(yi * yi);
    s[8] -= (double)(float)(_Float16)(yi * zi);
    s[9] -= (double)(float)(_Float16)(zi * zi);

    double cnt = s[0];
    double denom = fmax(cnt, 1.0);
    double mx = s[1] / denom, my = s[2] / denom, mz = s[3] / denom;
    const double invN = 1.0 / (double)N_PTS;
    double c00 = (s[4] - cnt * mx * mx) * invN;
    double c01 = (s[5] - cnt * mx * my) * invN;
    double c02 = (s[6] - cnt * mx * mz) * invN;
    double c11 = (s[7] - cnt * my * my) * invN;
    double c12 = (s[8] - cnt * my * mz) * invN;
    double c22 = (s[9] - cnt * mz * mz) * invN;

    double qm = (c00 + c11 + c22) / 3.0;
    double p1 = c01*c01 + c02*c02 + c12*c12;
    double a0 = c00 - qm, a1 = c11 - qm, a2 = c22 - qm;
    double p2 = a0*a0 + a1*a1 + a2*a2 + 2.0*p1;
    double e_lo, e_mid, e_hi;
    if (p2 < 1e-32) {
        e_lo = e_mid = e_hi = qm;
    } else {
        double p = sqrt(p2 / 6.0);
        double inv = 1.0 / p;
        double b00 = a0*inv, b11 = a1*inv, b22 = a2*inv;
        double b01 = c01*inv, b02 = c02*inv, b12 = c12*inv;
        double detB = b00*(b11*b22 - b12*b12)
                    - b01*(b01*b22 - b12*b02)
                    + b02*(b01*b12 - b11*b02);
        double r = 0.5 * detB;
        r = fmin(1.0, fmax(-1.0, r));
        double phi = acos(r) / 3.0;
        double two_p = 2.0 * p;
        e_hi = qm + two_p * cos(phi);
        e_lo = qm + two_p * cos(phi + 2.0943951023931953);
        e_mid = 3.0 * qm - e_hi - e_lo;
    }
    float e0 = (float)e_lo, e1 = (float)e_mid, e2 = (float)e_hi;

    float t[4];
    #pragma unroll
    for (int o = 0; o < 4; ++o)
        t[o] = fmaxf(e0 * ew1[o*3+0] + e1 * ew1[o*3+1] +
                     e2 * ew1[o*3+2] + eb1[o], 0.f);
    bf16x4 ov;
    #pragma unroll
    for (int o = 0; o < 4; ++o) {
        float h = t[0]*ew2[o*4+0] + t[1]*ew2[o*4+1] +
                  t[2]*ew2[o*4+2] + t[3]*ew2[o*4+3] + eb2[o];
        ov[o] = f2h(h);
    }
    *(bf16x4*)&zinT[((size_t)b * N_PTS + i) * 192 + 160] = ov;
}

// ---------------------------------------------------------------------------
// h1 [B][128][N] f32 -> zinT [B][N][192] fp16 ch 0..127, zero ch 164..191.
// ---------------------------------------------------------------------------
__global__ __launch_bounds__(256) void h1_transpose_kernel(
    const float* __restrict__ h1, short* __restrict__ zinT)
{
    const int b = blockIdx.y;
    const int n0 = blockIdx.x * 32;
    __shared__ float tile[128][33];
    #pragma unroll
    for (int it = 0; it < 16; ++it) {
        int idx = it * 256 + threadIdx.x;
        int c = idx >> 5, n = idx & 31;
        tile[c][n] = h1[((size_t)b * 128 + c) * N_PTS + n0 + n];
    }
    __syncthreads();
    #pragma unroll
    for (int it = 0; it < 16; ++it) {
        int idx = it * 256 + threadIdx.x;
        int c = idx & 127, n = idx >> 7;
        zinT[((size_t)b * N_PTS + n0 + n) * 192 + c] = f2h(tile[c][n]);
    }
    for (int idx = threadIdx.x; idx < 32 * 28; idx += 256) {
        int n = idx / 28, c = 164 + idx % 28;
        zinT[((size_t)b * N_PTS + n0 + n) * 192 + c] = 0;
    }
}

// ---------------------------------------------------------------------------
// h2_in [B][1024][N] f32 -> t_h2 [B][N][1024] fp16. Grid: (N/32, 8, B).
// ---------------------------------------------------------------------------
__global__ __launch_bounds__(256) void h2_transpose_kernel(
    const float* __restrict__ h2, short* __restrict__ t_h2)
{
    const int b = blockIdx.z;
    const int c0 = blockIdx.y * 128;
    const int n0 = blockIdx.x * 32;
    __shared__ float tile[128][33];
    #pragma unroll
    for (int it = 0; it < 16; ++it) {
        int idx = it * 256 + threadIdx.x;
        int c = idx >> 5, n = idx & 31;
        tile[c][n] = h2[((size_t)b * 1024 + c0 + c) * N_PTS + n0 + n];
    }
    __syncthreads();
    #pragma unroll
    for (int it = 0; it < 16; ++it) {
        int idx = it * 256 + threadIdx.x;
        int c = idx & 127, n = idx >> 7;
        t_h2[((size_t)b * N_PTS + n0 + n) * 1024 + c0 + c] = f2h(tile[c][n]);
    }
}

// ---------------------------------------------------------------------------
// All 6 weight conversions in ONE kernel. f32 -> fp16, k-linear, zero-padded.
// ---------------------------------------------------------------------------
struct WcArgs {
    const float* W[6];
    short* O[6];
    int M[6], K[6], Kp[6];
    int start[7];   // exclusive prefix of Mp*Kp
};

__global__ __launch_bounds__(256) void wconv_all_kernel(WcArgs a)
{
    int id = blockIdx.x * 256 + threadIdx.x;
    if (id >= a.start[6]) return;
    int l = 0;
    #pragma unroll
    for (int q = 1; q < 6; ++q) if (id >= a.start[q]) l = q;
    int local = id - a.start[l];
    int kp = a.Kp[l];
    int mrow = local / kp, k = local - mrow * kp;
    float v = (mrow < a.M[l] && k < a.K[l]) ? a.W[l][(size_t)mrow * a.K[l] + k] : 0.f;
    a.O[l][local] = f2h(v);
}

// ---------------------------------------------------------------------------
// fp16 MFMA GEMM, k-contiguous X (XT: [B][N][Kp] fp16). See round-7 notes.
// ---------------------------------------------------------------------------
template<int BM, int BN, bool OUTT>
__global__ __launch_bounds__(256) void mfma_gemm(
    const short* __restrict__ Wb, const short* __restrict__ XT,
    const float* __restrict__ bias, const float* __restrict__ scale,
    const float* __restrict__ shift, void* __restrict__ Yv,
    int M, int Kp, int ostride, size_t ybs)
{
    constexpr int LDW = 40;                    // padded LDS stride (shorts)
    constexpr int FM = BM / 32, FN = BN / 32;  // frags per wave
    constexpr int NCH = (BM + BN) * 4;         // 16B chunks per K-step
    constexpr int NREG = (NCH + 255) / 256;
    __shared__ __align__(16) short Wl[2][BM][LDW];
    __shared__ __align__(16) short Xl[2][BN][LDW];

    const int tid = threadIdx.x;
    const int lane = tid & 63, wave = tid >> 6;
    const int g = lane >> 4, r = lane & 15;
    const int wr = wave >> 1, wc = wave & 1;
    const int wm0 = wr * (BM / 2), wn0 = wc * (BN / 2);
    const int b = blockIdx.z;
    const int m0 = blockIdx.y * BM, n0 = blockIdx.x * BN;
    const int NT = Kp >> 5;

    f32x4 acc[FM][FN];
    #pragma unroll
    for (int i = 0; i < FM; ++i)
        #pragma unroll
        for (int jj = 0; jj < FN; ++jj)
            acc[i][jj] = (f32x4){0.f, 0.f, 0.f, 0.f};

    bf16x8 rg[NREG];

    auto load_regs = [&](int t) {
        #pragma unroll
        for (int u = 0; u < NREG; ++u) {
            int id = u * 256 + tid;
            if (id < NCH) {
                if (id < BM * 4) {
                    int m = id >> 2, c4 = id & 3;
                    rg[u] = *(const bf16x8*)&Wb[(size_t)(m0 + m) * Kp + (t << 5) + c4 * 8];
                } else {
                    int id2 = id - BM * 4;
                    int n = id2 >> 2, c4 = id2 & 3;
                    rg[u] = *(const bf16x8*)&XT[((size_t)b * N_PTS + n0 + n) * Kp + (t << 5) + c4 * 8];
                }
            }
        }
    };
    auto write_lds = [&](int nb) {
        #pragma unroll
        for (int u = 0; u < NREG; ++u) {
            int id = u * 256 + tid;
            if (id < NCH) {
                if (id < BM * 4) {
                    int m = id >> 2, c4 = id & 3;
                    *(bf16x8*)&Wl[nb][m][c4 * 8] = rg[u];
                } else {
                    int id2 = id - BM * 4;
                    int n = id2 >> 2, c4 = id2 & 3;
                    *(bf16x8*)&Xl[nb][n][c4 * 8] = rg[u];
                }
            }
        }
    };
    auto compute = [&](int cb) {
        #pragma unroll
        for (int fn = 0; fn < FN; ++fn) {
            bf16x8 bb = *(const bf16x8*)&Xl[cb][wn0 + fn * 16 + r][g * 8];
            #pragma unroll
            for (int fm = 0; fm < FM; ++fm) {
                bf16x8 a = *(const bf16x8*)&Wl[cb][wm0 + fm * 16 + r][g * 8];
                acc[fm][fn] = __builtin_amdgcn_mfma_f32_16x16x32_f16(
                    __builtin_bit_cast(f16x8, a),
                    __builtin_bit_cast(f16x8, bb),
                    acc[fm][fn], 0, 0, 0);
            }
        }
    };

    load_regs(0);
    write_lds(0);
    __syncthreads();
    for (int t = 0; t < NT; ++t) {
        int cb = t & 1;
        if (t + 1 < NT) load_regs(t + 1);
        compute(cb);
        if (t + 1 < NT) write_lds(cb ^ 1);
        __syncthreads();
    }

    if constexpr (OUTT) {
        short* Y = (short*)Yv;
        #pragma unroll
        for (int fm = 0; fm < FM; ++fm) {
            int mb = m0 + wm0 + fm * 16 + g * 4;
            if (mb < M) {
                float4 b4 = *(const float4*)&bias[mb];
                float4 s4 = *(const float4*)&scale[mb];
                float4 h4 = *(const float4*)&shift[mb];
                #pragma unroll
                for (int fn = 0; fn < FN; ++fn) {
                    int n = n0 + wn0 + fn * 16 + r;
                    f32x4 a = acc[fm][fn];
                    bf16x4 o;
                    o[0] = f2h(fmaxf(fmaf(a[0] + b4.x, s4.x, h4.x), 0.f));
                    o[1] = f2h(fmaxf(fmaf(a[1] + b4.y, s4.y, h4.y), 0.f));
                    o[2] = f2h(fmaxf(fmaf(a[2] + b4.z, s4.z, h4.z), 0.f));
                    o[3] = f2h(fmaxf(fmaf(a[3] + b4.w, s4.w, h4.w), 0.f));
                    *(bf16x4*)&Y[((size_t)b * N_PTS + n) * ostride + mb] = o;
                }
            }
        }
    } else {
        float* Y = (float*)Yv;
        #pragma unroll
        for (int fm = 0; fm < FM; ++fm) {
            int mbase = m0 + wm0 + fm * 16 + g * 4;
            #pragma unroll
            for (int e = 0; e < 4; ++e) {
                int mm = mbase + e;
                if (mm >= M) continue;
                float bs = bias[mm], sc = scale[mm], sh = shift[mm];
                #pragma unroll
                for (int fn = 0; fn < FN; ++fn) {
                    int n = n0 + wn0 + fn * 16 + r;
                    float v = fmaxf(fmaf(acc[fm][fn][e] + bs, sc, sh), 0.f);
                    Y[(size_t)b * ybs + (size_t)mm * N_PTS + n] = v;
                }
            }
        }
    }
}

// ---------------------------------------------------------------------------
extern "C" void kernel_launch(void* const* d_in, const int* in_sizes, int n_in,
                              void* d_out, int out_size, void* d_ws, size_t ws_size,
                              hipStream_t stream)
{
    const float* xyz   = (const float*)d_in[0];
    const float* h1    = (const float*)d_in[1];
    const float* h2_in = (const float*)d_in[2];
    const float* dg_w1 = (const float*)d_in[3];
    const float* dg_b1 = (const float*)d_in[4];
    const float* dg_s1 = (const float*)d_in[5];
    const float* dg_t1 = (const float*)d_in[6];
    const float* dg_w2 = (const float*)d_in[7];
    const float* dg_b2 = (const float*)d_in[8];
    const float* dg_s2 = (const float*)d_in[9];
    const float* dg_t2 = (const float*)d_in[10];
    const float* dg_w3 = (const float*)d_in[11];
    const float* dg_b3 = (const float*)d_in[12];
    const float* dg_s3 = (const float*)d_in[13];
    const float* dg_t3 = (const float*)d_in[14];
    const float* ed_w1 = (const float*)d_in[15];
    const float* ed_b1 = (const float*)d_in[16];
    const float* ed_w2 = (const float*)d_in[17];
    const float* ed_b2 = (const float*)d_in[18];
    const float* w1 = (const float*)d_in[19];
    const float* b1 = (const float*)d_in[20];
    const float* s1 = (const float*)d_in[21];
    const float* t1 = (const float*)d_in[22];
    const float* w2 = (const float*)d_in[23];
    const float* b2 = (const float*)d_in[24];
    const float* s2 = (const float*)d_in[25];
    const float* t2 = (const float*)d_in[26];
    const float* w3 = (const float*)d_in[27];
    const float* b3 = (const float*)d_in[28];
    const float* s3 = (const float*)d_in[29];
    const float* t3 = (const float*)d_in[30];

    float* out = (float*)d_out;

    // workspace layout (bufB aliases t_h2, bufD aliases bufA)
    char* ws = (char*)d_ws;
    size_t off = 0;
    auto alloc = [&](size_t bytes) {
        char* p = ws + off;
        off += (bytes + 255) & ~(size_t)255;
        return p;
    };
    unsigned int* maxd2 = (unsigned int*)alloc(256);
    short* wb1  = (short*)alloc((size_t)256 * 1024 * 2);
    short* wb2  = (short*)alloc((size_t)64  * 256  * 2);
    short* wb3  = (short*)alloc((size_t)64  * 64   * 2);
    short* wbf1 = (short*)alloc((size_t)512 * 192  * 2);
    short* wbf2 = (short*)alloc((size_t)256 * 512  * 2);
    short* wbf3 = (short*)alloc((size_t)128 * 256  * 2);
    short* zinT = (short*)alloc((size_t)BATCH * N_PTS * 192 * 2);   // 6.3 MB
    short* t_h2 = (short*)alloc((size_t)BATCH * N_PTS * 1024 * 2);  // 33.5 MB
    short* bufA = (short*)alloc((size_t)BATCH * N_PTS * 256 * 2);   // 8.4 MB
    short* bufC = (short*)alloc((size_t)BATCH * N_PTS * 64 * 2);    // 2.1 MB
    float* pbuf = (float*)alloc((size_t)BATCH * JS * N_PTS * 16 * 4); // 8.4 MB
    short* bufB = t_h2;   // [B][N][512] fp16 (t_h2 dead after DG1)
    short* bufD = bufA;   // [B][N][256] fp16 (bufA dead after DG2)

    init_maxd2_kernel<<<1, 64, 0, stream>>>(maxd2);

    // all weight conversions in one launch
    {
        WcArgs a;
        const float* Wp[6] = {dg_w1, dg_w2, dg_w3, w1, w2, w3};
        short* Op[6] = {wb1, wb2, wb3, wbf1, wbf2, wbf3};
        int Mv[6] = {256, 64, 32, 512, 256, 128};
        int Kv[6] = {1024, 256, 64, 164, 512, 256};
        int Mp[6] = {256, 64, 64, 512, 256, 128};
        int Kp[6] = {1024, 256, 64, 192, 512, 256};
        int acc0 = 0;
        for (int l = 0; l < 6; ++l) {
            a.W[l] = Wp[l]; a.O[l] = Op[l];
            a.M[l] = Mv[l]; a.K[l] = Kv[l]; a.Kp[l] = Kp[l];
            a.start[l] = acc0;
            acc0 += Mp[l] * Kp[l];
        }
        a.start[6] = acc0;
        wconv_all_kernel<<<(acc0 + 255) / 256, 256, 0, stream>>>(a);
    }

    // eigen branch
    dim3 gsplit(N_PTS / 64, JS, BATCH);
    radius_max_kernel<<<gsplit, 256, 0, stream>>>(xyz, maxd2);
    eigen_accum_kernel<<<gsplit, 256, 0, stream>>>(xyz, maxd2, pbuf);
    eigen_finalize_kernel<<<(BATCH * N_PTS + 255) / 256, 256, 0, stream>>>(
        xyz, pbuf, ed_w1, ed_b1, ed_w2, ed_b2, zinT, out);

    // layout transposes
    h2_transpose_kernel<<<dim3(N_PTS / 32, 8, BATCH), 256, 0, stream>>>(h2_in, t_h2);
    h1_transpose_kernel<<<dim3(N_PTS / 32, BATCH), 256, 0, stream>>>(h1, zinT);

    // GEMM chain (all X k-contiguous)
    // DG1: 1024 -> 256
    mfma_gemm<64, 64, true><<<dim3(N_PTS/64, 4, BATCH), 256, 0, stream>>>(
        wb1, t_h2, dg_b1, dg_s1, dg_t1, bufA, 256, 1024, 256, 0);
    // DG2: 256 -> 64
    mfma_gemm<64, 32, true><<<dim3(N_PTS/32, 1, BATCH), 256, 0, stream>>>(
        wb2, bufA, dg_b2, dg_s2, dg_t2, bufC, 64, 256, 64, 0);
    // DG3: 64 -> 32 (zinT ch 128..159)
    mfma_gemm<64, 32, true><<<dim3(N_PTS/32, 1, BATCH), 256, 0, stream>>>(
        wb3, bufC, dg_b3, dg_s3, dg_t3, zinT + 128, 32, 64, 192, 0);
    // F1: 192 -> 512
    mfma_gemm<128, 64, true><<<dim3(N_PTS/64, 4, BATCH), 256, 0, stream>>>(
        wbf1, zinT, b1, s1, t1, bufB, 512, 192, 512, 0);
    // F2: 512 -> 256
    mfma_gemm<64, 64, true><<<dim3(N_PTS/64, 4, BATCH), 256, 0, stream>>>(
        wbf2, bufB, b2, s2, t2, bufD, 256, 512, 256, 0);
    // F3: 256 -> 128 (f32 [b][m][n] into d_out after xyz)
    mfma_gemm<64, 32, false><<<dim3(N_PTS/32, 2, BATCH), 256, 0, stream>>>(
        wbf3, bufD, b3, s3, t3, out + (size_t)BATCH * N_PTS * 3, 128, 256, 0,
        (size_t)128 * N_PTS);
}

// Round 10
// 139.871 us; speedup vs baseline: 1.3604x; 1.1388x over previous
//
#include <hip/hip_runtime.h>
#include <math.h>

#define N_PTS 4096
#define BATCH 4
#define JS 8                  // j-split factor
#define JCH (N_PTS / JS)      // 512 points per j-chunk

typedef short bf16x8 __attribute__((ext_vector_type(8)));
typedef short bf16x4 __attribute__((ext_vector_type(4)));
typedef float f32x4 __attribute__((ext_vector_type(4)));
typedef _Float16 f16x8 __attribute__((ext_vector_type(8)));

// f32 -> fp16 (RNE), bit pattern in short
__device__ inline short f2h(float f) {
    _Float16 h = (_Float16)f;
    return __builtin_bit_cast(short, h);
}

// ---------------------------------------------------------------------------
// Per-batch max pairwise squared distance, TRIANGULAR: blocks whose j-chunk
// is entirely below the i-chunk only produce duplicate (symmetric) pairs ->
// early-exit. Coverage: any pair i<=j has ci=i/64 <= 8*(j/512)+7. Grid:
// (N/64, JS, B), 256 threads.
// ---------------------------------------------------------------------------
__global__ __launch_bounds__(256) void radius_max_kernel(
    const float* __restrict__ xyz, unsigned int* __restrict__ maxd2)
{
    if ((int)blockIdx.x >= 8 * (int)blockIdx.y + 8) return;   // uniform exit
    const int b = blockIdx.z;
    __shared__ float4 sj[JCH];
    const float* xb = xyz + (size_t)b * N_PTS * 3;
    const int j0 = blockIdx.y * JCH;
    for (int idx = threadIdx.x; idx < JCH; idx += 256) {
        int j = j0 + idx;
        float x = xb[j*3+0], y = xb[j*3+1], z = xb[j*3+2];
        sj[idx] = make_float4(x, y, z, fmaf(x, x, fmaf(y, y, z * z)));
    }
    __syncthreads();
    const int il = threadIdx.x & 63;
    const int jq = threadIdx.x >> 6;
    const int i = blockIdx.x * 64 + il;
    const float xi = xb[i*3+0], yi = xb[i*3+1], zi = xb[i*3+2];
    const float x2i = fmaf(xi, xi, fmaf(yi, yi, zi * zi));
    float m = 0.f;
    const int jb = jq * (JCH / 4);
    #pragma unroll 4
    for (int j = jb; j < jb + JCH / 4; ++j) {
        float4 p = sj[j];
        float dot = fmaf(xi, p.x, fmaf(yi, p.y, zi * p.z));
        float d2 = fmaf(-2.f, dot, x2i + p.w);
        m = fmaxf(m, d2);
    }
    for (int off = 32; off >= 1; off >>= 1) m = fmaxf(m, __shfl_down(m, off));
    __shared__ float wred[4];
    if ((threadIdx.x & 63) == 0) wred[threadIdx.x >> 6] = m;
    __syncthreads();
    if (threadIdx.x == 0) {
        float mm = fmaxf(fmaxf(wred[0], wred[1]), fmaxf(wred[2], wred[3]));
        atomicMax(&maxd2[b], __float_as_uint(mm));
    }
}

// ---------------------------------------------------------------------------
// Eigen accumulate via MFMA (round-9 validated). Grid: (N/64, JS, B).
// ---------------------------------------------------------------------------
__global__ __launch_bounds__(256) void eigen_accum_kernel(
    const float* __restrict__ xyz, const unsigned int* __restrict__ maxd2,
    float* __restrict__ pbuf)
{
    const int b = blockIdx.z, js = blockIdx.y;
    __shared__ __align__(16) float4 sj4[JCH];
    __shared__ __align__(16) _Float16 Ft[16][JCH + 8];
    const float* xb = xyz + (size_t)b * N_PTS * 3;
    const int j0g = js * JCH;
    for (int idx = threadIdx.x; idx < JCH; idx += 256) {
        int j = j0g + idx;
        float x = xb[j*3+0], y = xb[j*3+1], z = xb[j*3+2];
        sj4[idx] = make_float4(x, y, z, fmaf(x, x, fmaf(y, y, z * z)));
        Ft[0][idx] = (_Float16)1.f;
        Ft[1][idx] = (_Float16)x;
        Ft[2][idx] = (_Float16)y;
        Ft[3][idx] = (_Float16)z;
        Ft[4][idx] = (_Float16)(x * x);
        Ft[5][idx] = (_Float16)(x * y);
        Ft[6][idx] = (_Float16)(x * z);
        Ft[7][idx] = (_Float16)(y * y);
        Ft[8][idx] = (_Float16)(y * z);
        Ft[9][idx] = (_Float16)(z * z);
        Ft[10][idx] = (_Float16)0.f; Ft[11][idx] = (_Float16)0.f;
        Ft[12][idx] = (_Float16)0.f; Ft[13][idx] = (_Float16)0.f;
        Ft[14][idx] = (_Float16)0.f; Ft[15][idx] = (_Float16)0.f;
    }
    __syncthreads();

    const int lane = threadIdx.x & 63, wave = threadIdx.x >> 6;
    const int r = lane & 15, g = lane >> 4;
    const int i_wf = blockIdx.x * 64 + wave * 16 + r;
    const float xi = xb[i_wf*3+0], yi = xb[i_wf*3+1], zi = xb[i_wf*3+2];
    const float x2i = fmaf(xi, xi, fmaf(yi, yi, zi * zi));
    const float r2 = 0.01f * __uint_as_float(maxd2[b]);

    f32x4 acc = (f32x4){0.f, 0.f, 0.f, 0.f};
    #pragma unroll 4
    for (int t = 0; t < JCH / 32; ++t) {
        const int jb = t * 32 + g * 8;
        f16x8 wfv;
        #pragma unroll
        for (int s = 0; s < 8; ++s) {
            float4 p = sj4[jb + s];
            float dot = fmaf(xi, p.x, fmaf(yi, p.y, zi * p.z));
            float d2 = fmaf(-2.f, dot, x2i + p.w);
            wfv[s] = (d2 < r2) ? (_Float16)1.f : (_Float16)0.f;
        }
        f16x8 fv = *(const f16x8*)&Ft[r][jb];
        acc = __builtin_amdgcn_mfma_f32_16x16x32_f16(wfv, fv, acc, 0, 0, 0);
    }

    const int i_out = blockIdx.x * 64 + wave * 16 + g * 4;
    float* dst = pbuf + ((size_t)(b * JS + js) * N_PTS + i_out) * 16 + r;
    #pragma unroll
    for (int e = 0; e < 4; ++e) dst[(size_t)e * 16] = acc[e];
}

// ---------------------------------------------------------------------------
// Eigen finalize (+ xyz passthrough). Round-9 validated.
// ---------------------------------------------------------------------------
__global__ __launch_bounds__(256) void eigen_finalize_kernel(
    const float* __restrict__ xyz, const float* __restrict__ pbuf,
    const float* __restrict__ ew1, const float* __restrict__ eb1,
    const float* __restrict__ ew2, const float* __restrict__ eb2,
    short* __restrict__ zinT, float* __restrict__ out)
{
    int id = blockIdx.x * 256 + threadIdx.x;
    if (id >= BATCH * N_PTS) return;
    int b = id >> 12, i = id & (N_PTS - 1);

    out[id*3+0] = xyz[id*3+0];
    out[id*3+1] = xyz[id*3+1];
    out[id*3+2] = xyz[id*3+2];

    double s[10] = {0,0,0,0,0,0,0,0,0,0};
    for (int js = 0; js < JS; ++js) {
        const float* src = pbuf + ((size_t)(b * JS + js) * N_PTS + i) * 16;
        #pragma unroll
        for (int q = 0; q < 10; ++q) s[q] += (double)src[q];
    }
    const float* xb = xyz + (size_t)b * N_PTS * 3;
    float xi = xb[i*3+0], yi = xb[i*3+1], zi = xb[i*3+2];
    s[0] -= 1.0;
    s[1] -= (double)(float)(_Float16)xi;
    s[2] -= (double)(float)(_Float16)yi;
    s[3] -= (double)(float)(_Float16)zi;
    s[4] -= (double)(float)(_Float16)(xi * xi);
    s[5] -= (double)(float)(_Float16)(xi * yi);
    s[6] -= (double)(float)(_Float16)(xi * zi);
    s[7] -= (double)(float)(_Float16)(yi * yi);
    s[8] -= (double)(float)(_Float16)(yi * zi);
    s[9] -= (double)(float)(_Float16)(zi * zi);

    double cnt = s[0];
    double denom = fmax(cnt, 1.0);
    double mx = s[1] / denom, my = s[2] / denom, mz = s[3] / denom;
    const double invN = 1.0 / (double)N_PTS;
    double c00 = (s[4] - cnt * mx * mx) * invN;
    double c01 = (s[5] - cnt * mx * my) * invN;
    double c02 = (s[6] - cnt * mx * mz) * invN;
    double c11 = (s[7] - cnt * my * my) * invN;
    double c12 = (s[8] - cnt * my * mz) * invN;
    double c22 = (s[9] - cnt * mz * mz) * invN;

    double qm = (c00 + c11 + c22) / 3.0;
    double p1 = c01*c01 + c02*c02 + c12*c12;
    double a0 = c00 - qm, a1 = c11 - qm, a2 = c22 - qm;
    double p2 = a0*a0 + a1*a1 + a2*a2 + 2.0*p1;
    double e_lo, e_mid, e_hi;
    if (p2 < 1e-32) {
        e_lo = e_mid = e_hi = qm;
    } else {
        double p = sqrt(p2 / 6.0);
        double inv = 1.0 / p;
        double b00 = a0*inv, b11 = a1*inv, b22 = a2*inv;
        double b01 = c01*inv, b02 = c02*inv, b12 = c12*inv;
        double detB = b00*(b11*b22 - b12*b12)
                    - b01*(b01*b22 - b12*b02)
                    + b02*(b01*b12 - b11*b02);
        double r = 0.5 * detB;
        r = fmin(1.0, fmax(-1.0, r));
        double phi = acos(r) / 3.0;
        double two_p = 2.0 * p;
        e_hi = qm + two_p * cos(phi);
        e_lo = qm + two_p * cos(phi + 2.0943951023931953);
        e_mid = 3.0 * qm - e_hi - e_lo;
    }
    float e0 = (float)e_lo, e1 = (float)e_mid, e2 = (float)e_hi;

    float t[4];
    #pragma unroll
    for (int o = 0; o < 4; ++o)
        t[o] = fmaxf(e0 * ew1[o*3+0] + e1 * ew1[o*3+1] +
                     e2 * ew1[o*3+2] + eb1[o], 0.f);
    bf16x4 ov;
    #pragma unroll
    for (int o = 0; o < 4; ++o) {
        float h = t[0]*ew2[o*4+0] + t[1]*ew2[o*4+1] +
                  t[2]*ew2[o*4+2] + t[3]*ew2[o*4+3] + eb2[o];
        ov[o] = f2h(h);
    }
    *(bf16x4*)&zinT[((size_t)b * N_PTS + i) * 192 + 160] = ov;
}

// ---------------------------------------------------------------------------
// h1 [B][128][N] f32 -> zinT [B][N][192] fp16 ch 0..127, zero ch 164..191.
// ---------------------------------------------------------------------------
__global__ __launch_bounds__(256) void h1_transpose_kernel(
    const float* __restrict__ h1, short* __restrict__ zinT)
{
    const int b = blockIdx.y;
    const int n0 = blockIdx.x * 32;
    __shared__ float tile[128][33];
    #pragma unroll
    for (int it = 0; it < 16; ++it) {
        int idx = it * 256 + threadIdx.x;
        int c = idx >> 5, n = idx & 31;
        tile[c][n] = h1[((size_t)b * 128 + c) * N_PTS + n0 + n];
    }
    __syncthreads();
    #pragma unroll
    for (int it = 0; it < 16; ++it) {
        int idx = it * 256 + threadIdx.x;
        int c = idx & 127, n = idx >> 7;
        zinT[((size_t)b * N_PTS + n0 + n) * 192 + c] = f2h(tile[c][n]);
    }
    for (int idx = threadIdx.x; idx < 32 * 28; idx += 256) {
        int n = idx / 28, c = 164 + idx % 28;
        zinT[((size_t)b * N_PTS + n0 + n) * 192 + c] = 0;
    }
}

// ---------------------------------------------------------------------------
// All 6 weight conversions in ONE kernel (+ maxd2 init in block 0).
// ---------------------------------------------------------------------------
struct WcArgs {
    const float* W[6];
    short* O[6];
    int M[6], K[6], Kp[6];
    int start[7];
    unsigned int* maxd2;
};

__global__ __launch_bounds__(256) void wconv_all_kernel(WcArgs a)
{
    if (blockIdx.x == 0 && threadIdx.x < BATCH) a.maxd2[threadIdx.x] = 0u;
    int id = blockIdx.x * 256 + threadIdx.x;
    if (id >= a.start[6]) return;
    int l = 0;
    #pragma unroll
    for (int q = 1; q < 6; ++q) if (id >= a.start[q]) l = q;
    int local = id - a.start[l];
    int kp = a.Kp[l];
    int mrow = local / kp, k = local - mrow * kp;
    float v = (mrow < a.M[l] && k < a.K[l]) ? a.W[l][(size_t)mrow * a.K[l] + k] : 0.f;
    a.O[l][local] = f2h(v);
}

// ---------------------------------------------------------------------------
// DG1 FUSED: reads h2_in [B][1024][N] f32 DIRECTLY (no t_h2 round trip).
// Per K-step: coalesced f32 read -> padded f32 LDS transpose tile tt[32][66]
// (proven transpose pattern) -> pack fp16 -> vector b128 write into the
// standard Xl[n][LDW] layout. Fragment/MFMA/epilogue paths byte-identical to
// the validated template. 2 syncs per K-step. BM=BN=64, K=1024, NT=32.
// Out: bufA [B][N][256] fp16 at channel m (OUTT epilogue).
// ---------------------------------------------------------------------------
__global__ __launch_bounds__(256) void dg1_fused_kernel(
    const short* __restrict__ Wb, const float* __restrict__ h2,
    const float* __restrict__ bias, const float* __restrict__ scale,
    const float* __restrict__ shift, short* __restrict__ Y)
{
    constexpr int LDW = 40;
    constexpr int NT = 32;      // K = 1024
    __shared__ __align__(16) short Wl[2][64][LDW];
    __shared__ __align__(16) short Xl[2][64][LDW];
    __shared__ __align__(16) float tt[32][66];

    const int tid = threadIdx.x;
    const int lane = tid & 63, wave = tid >> 6;
    const int g = lane >> 4, r = lane & 15;
    const int wr = wave >> 1, wc = wave & 1;
    const int wm0 = wr * 32, wn0 = wc * 32;
    const int b = blockIdx.z;
    const int m0 = blockIdx.y * 64, n0 = blockIdx.x * 64;

    // staging mappings
    const int wm = tid >> 2, wc4 = tid & 3;       // W: row, 16B-chunk
    const int kk = tid >> 3, nq = (tid & 7) * 8;  // X read: k-row, n-octet
    const int tn = tid & 63, tc4 = tid >> 6;      // transpose read: col, k-block

    f32x4 acc[2][2];
    #pragma unroll
    for (int i = 0; i < 2; ++i)
        #pragma unroll
        for (int j = 0; j < 2; ++j) acc[i][j] = (f32x4){0.f,0.f,0.f,0.f};

    bf16x8 wreg;
    float4 xr0, xr1;

    auto load_regs = [&](int t) {
        wreg = *(const bf16x8*)&Wb[(size_t)(m0 + wm) * 1024 + (t << 5) + wc4 * 8];
        const float* src = &h2[((size_t)b * 1024 + (t << 5) + kk) * N_PTS + n0 + nq];
        xr0 = *(const float4*)src;
        xr1 = *(const float4*)(src + 4);
    };
    auto write_tt = [&]() {
        *(float4*)&tt[kk][nq] = xr0;
        *(float4*)&tt[kk][nq + 4] = xr1;
    };
    auto fill_lds = [&](int nb) {
        *(bf16x8*)&Wl[nb][wm][wc4 * 8] = wreg;
        bf16x8 v;
        #pragma unroll
        for (int s = 0; s < 8; ++s) v[s] = f2h(tt[tc4 * 8 + s][tn]);
        *(bf16x8*)&Xl[nb][tn][tc4 * 8] = v;
    };
    auto compute = [&](int cb) {
        #pragma unroll
        for (int fn = 0; fn < 2; ++fn) {
            bf16x8 bb = *(const bf16x8*)&Xl[cb][wn0 + fn * 16 + r][g * 8];
            #pragma unroll
            for (int fm = 0; fm < 2; ++fm) {
                bf16x8 a = *(const bf16x8*)&Wl[cb][wm0 + fm * 16 + r][g * 8];
                acc[fm][fn] = __builtin_amdgcn_mfma_f32_16x16x32_f16(
                    __builtin_bit_cast(f16x8, a),
                    __builtin_bit_cast(f16x8, bb),
                    acc[fm][fn], 0, 0, 0);
            }
        }
    };

    // prologue: tile 0
    load_regs(0);
    write_tt();
    __syncthreads();
    fill_lds(0);
    __syncthreads();

    for (int t = 0; t < NT; ++t) {
        int cb = t & 1;
        if (t + 1 < NT) load_regs(t + 1);
        compute(cb);
        if (t + 1 < NT) write_tt();
        __syncthreads();                 // compute(cb) done; tt[t+1] visible
        if (t + 1 < NT) fill_lds(cb ^ 1);
        __syncthreads();                 // Xl/Wl[cb^1] ready for next iter
    }

    // epilogue: fp16 transposed out into Y[b][n][256] at channel mb
    #pragma unroll
    for (int fm = 0; fm < 2; ++fm) {
        int mb = m0 + wm0 + fm * 16 + g * 4;
        float4 b4 = *(const float4*)&bias[mb];
        float4 s4 = *(const float4*)&scale[mb];
        float4 h4 = *(const float4*)&shift[mb];
        #pragma unroll
        for (int fn = 0; fn < 2; ++fn) {
            int n = n0 + wn0 + fn * 16 + r;
            f32x4 a = acc[fm][fn];
            bf16x4 o;
            o[0] = f2h(fmaxf(fmaf(a[0] + b4.x, s4.x, h4.x), 0.f));
            o[1] = f2h(fmaxf(fmaf(a[1] + b4.y, s4.y, h4.y), 0.f));
            o[2] = f2h(fmaxf(fmaf(a[2] + b4.z, s4.z, h4.z), 0.f));
            o[3] = f2h(fmaxf(fmaf(a[3] + b4.w, s4.w, h4.w), 0.f));
            *(bf16x4*)&Y[((size_t)b * N_PTS + n) * 256 + mb] = o;
        }
    }
}

// ---------------------------------------------------------------------------
// fp16 MFMA GEMM, k-contiguous X (XT: [B][N][Kp] fp16). Rounds 7-9 validated.
// ---------------------------------------------------------------------------
template<int BM, int BN, bool OUTT>
__global__ __launch_bounds__(256) void mfma_gemm(
    const short* __restrict__ Wb, const short* __restrict__ XT,
    const float* __restrict__ bias, const float* __restrict__ scale,
    const float* __restrict__ shift, void* __restrict__ Yv,
    int M, int Kp, int ostride, size_t ybs)
{
    constexpr int LDW = 40;
    constexpr int FM = BM / 32, FN = BN / 32;
    constexpr int NCH = (BM + BN) * 4;
    constexpr int NREG = (NCH + 255) / 256;
    __shared__ __align__(16) short Wl[2][BM][LDW];
    __shared__ __align__(16) short Xl[2][BN][LDW];

    const int tid = threadIdx.x;
    const int lane = tid & 63, wave = tid >> 6;
    const int g = lane >> 4, r = lane & 15;
    const int wr = wave >> 1, wc = wave & 1;
    const int wm0 = wr * (BM / 2), wn0 = wc * (BN / 2);
    const int b = blockIdx.z;
    const int m0 = blockIdx.y * BM, n0 = blockIdx.x * BN;
    const int NT = Kp >> 5;

    f32x4 acc[FM][FN];
    #pragma unroll
    for (int i = 0; i < FM; ++i)
        #pragma unroll
        for (int jj = 0; jj < FN; ++jj)
            acc[i][jj] = (f32x4){0.f, 0.f, 0.f, 0.f};

    bf16x8 rg[NREG];

    auto load_regs = [&](int t) {
        #pragma unroll
        for (int u = 0; u < NREG; ++u) {
            int id = u * 256 + tid;
            if (id < NCH) {
                if (id < BM * 4) {
                    int m = id >> 2, c4 = id & 3;
                    rg[u] = *(const bf16x8*)&Wb[(size_t)(m0 + m) * Kp + (t << 5) + c4 * 8];
                } else {
                    int id2 = id - BM * 4;
                    int n = id2 >> 2, c4 = id2 & 3;
                    rg[u] = *(const bf16x8*)&XT[((size_t)b * N_PTS + n0 + n) * Kp + (t << 5) + c4 * 8];
                }
            }
        }
    };
    auto write_lds = [&](int nb) {
        #pragma unroll
        for (int u = 0; u < NREG; ++u) {
            int id = u * 256 + tid;
            if (id < NCH) {
                if (id < BM * 4) {
                    int m = id >> 2, c4 = id & 3;
                    *(bf16x8*)&Wl[nb][m][c4 * 8] = rg[u];
                } else {
                    int id2 = id - BM * 4;
                    int n = id2 >> 2, c4 = id2 & 3;
                    *(bf16x8*)&Xl[nb][n][c4 * 8] = rg[u];
                }
            }
        }
    };
    auto compute = [&](int cb) {
        #pragma unroll
        for (int fn = 0; fn < FN; ++fn) {
            bf16x8 bb = *(const bf16x8*)&Xl[cb][wn0 + fn * 16 + r][g * 8];
            #pragma unroll
            for (int fm = 0; fm < FM; ++fm) {
                bf16x8 a = *(const bf16x8*)&Wl[cb][wm0 + fm * 16 + r][g * 8];
                acc[fm][fn] = __builtin_amdgcn_mfma_f32_16x16x32_f16(
                    __builtin_bit_cast(f16x8, a),
                    __builtin_bit_cast(f16x8, bb),
                    acc[fm][fn], 0, 0, 0);
            }
        }
    };

    load_regs(0);
    write_lds(0);
    __syncthreads();
    for (int t = 0; t < NT; ++t) {
        int cb = t & 1;
        if (t + 1 < NT) load_regs(t + 1);
        compute(cb);
        if (t + 1 < NT) write_lds(cb ^ 1);
        __syncthreads();
    }

    if constexpr (OUTT) {
        short* Y = (short*)Yv;
        #pragma unroll
        for (int fm = 0; fm < FM; ++fm) {
            int mb = m0 + wm0 + fm * 16 + g * 4;
            if (mb < M) {
                float4 b4 = *(const float4*)&bias[mb];
                float4 s4 = *(const float4*)&scale[mb];
                float4 h4 = *(const float4*)&shift[mb];
                #pragma unroll
                for (int fn = 0; fn < FN; ++fn) {
                    int n = n0 + wn0 + fn * 16 + r;
                    f32x4 a = acc[fm][fn];
                    bf16x4 o;
                    o[0] = f2h(fmaxf(fmaf(a[0] + b4.x, s4.x, h4.x), 0.f));
                    o[1] = f2h(fmaxf(fmaf(a[1] + b4.y, s4.y, h4.y), 0.f));
                    o[2] = f2h(fmaxf(fmaf(a[2] + b4.z, s4.z, h4.z), 0.f));
                    o[3] = f2h(fmaxf(fmaf(a[3] + b4.w, s4.w, h4.w), 0.f));
                    *(bf16x4*)&Y[((size_t)b * N_PTS + n) * ostride + mb] = o;
                }
            }
        }
    } else {
        float* Y = (float*)Yv;
        #pragma unroll
        for (int fm = 0; fm < FM; ++fm) {
            int mbase = m0 + wm0 + fm * 16 + g * 4;
            #pragma unroll
            for (int e = 0; e < 4; ++e) {
                int mm = mbase + e;
                if (mm >= M) continue;
                float bs = bias[mm], sc = scale[mm], sh = shift[mm];
                #pragma unroll
                for (int fn = 0; fn < FN; ++fn) {
                    int n = n0 + wn0 + fn * 16 + r;
                    float v = fmaxf(fmaf(acc[fm][fn][e] + bs, sc, sh), 0.f);
                    Y[(size_t)b * ybs + (size_t)mm * N_PTS + n] = v;
                }
            }
        }
    }
}

// ---------------------------------------------------------------------------
extern "C" void kernel_launch(void* const* d_in, const int* in_sizes, int n_in,
                              void* d_out, int out_size, void* d_ws, size_t ws_size,
                              hipStream_t stream)
{
    const float* xyz   = (const float*)d_in[0];
    const float* h1    = (const float*)d_in[1];
    const float* h2_in = (const float*)d_in[2];
    const float* dg_w1 = (const float*)d_in[3];
    const float* dg_b1 = (const float*)d_in[4];
    const float* dg_s1 = (const float*)d_in[5];
    const float* dg_t1 = (const float*)d_in[6];
    const float* dg_w2 = (const float*)d_in[7];
    const float* dg_b2 = (const float*)d_in[8];
    const float* dg_s2 = (const float*)d_in[9];
    const float* dg_t2 = (const float*)d_in[10];
    const float* dg_w3 = (const float*)d_in[11];
    const float* dg_b3 = (const float*)d_in[12];
    const float* dg_s3 = (const float*)d_in[13];
    const float* dg_t3 = (const float*)d_in[14];
    const float* ed_w1 = (const float*)d_in[15];
    const float* ed_b1 = (const float*)d_in[16];
    const float* ed_w2 = (const float*)d_in[17];
    const float* ed_b2 = (const float*)d_in[18];
    const float* w1 = (const float*)d_in[19];
    const float* b1 = (const float*)d_in[20];
    const float* s1 = (const float*)d_in[21];
    const float* t1 = (const float*)d_in[22];
    const float* w2 = (const float*)d_in[23];
    const float* b2 = (const float*)d_in[24];
    const float* s2 = (const float*)d_in[25];
    const float* t2 = (const float*)d_in[26];
    const float* w3 = (const float*)d_in[27];
    const float* b3 = (const float*)d_in[28];
    const float* s3 = (const float*)d_in[29];
    const float* t3 = (const float*)d_in[30];

    float* out = (float*)d_out;

    // workspace layout (t_h2 eliminated; bufD aliases bufB tail-safe? keep separate)
    char* ws = (char*)d_ws;
    size_t off = 0;
    auto alloc = [&](size_t bytes) {
        char* p = ws + off;
        off += (bytes + 255) & ~(size_t)255;
        return p;
    };
    unsigned int* maxd2 = (unsigned int*)alloc(256);
    short* wb1  = (short*)alloc((size_t)256 * 1024 * 2);
    short* wb2  = (short*)alloc((size_t)64  * 256  * 2);
    short* wb3  = (short*)alloc((size_t)64  * 64   * 2);
    short* wbf1 = (short*)alloc((size_t)512 * 192  * 2);
    short* wbf2 = (short*)alloc((size_t)256 * 512  * 2);
    short* wbf3 = (short*)alloc((size_t)128 * 256  * 2);
    short* zinT = (short*)alloc((size_t)BATCH * N_PTS * 192 * 2);   // 6.3 MB
    short* bufA = (short*)alloc((size_t)BATCH * N_PTS * 256 * 2);   // 8.4 MB
    short* bufB = (short*)alloc((size_t)BATCH * N_PTS * 512 * 2);   // 16.8 MB
    short* bufC = (short*)alloc((size_t)BATCH * N_PTS * 64 * 2);    // 2.1 MB
    float* pbuf = (float*)alloc((size_t)BATCH * JS * N_PTS * 16 * 4); // 8.4 MB
    short* bufD = bufA;   // [B][N][256] fp16 (bufA dead after DG2)

    // all weight conversions + maxd2 init in one launch
    {
        WcArgs a;
        const float* Wp[6] = {dg_w1, dg_w2, dg_w3, w1, w2, w3};
        short* Op[6] = {wb1, wb2, wb3, wbf1, wbf2, wbf3};
        int Mv[6] = {256, 64, 32, 512, 256, 128};
        int Kv[6] = {1024, 256, 64, 164, 512, 256};
        int Mp[6] = {256, 64, 64, 512, 256, 128};
        int Kp[6] = {1024, 256, 64, 192, 512, 256};
        int acc0 = 0;
        for (int l = 0; l < 6; ++l) {
            a.W[l] = Wp[l]; a.O[l] = Op[l];
            a.M[l] = Mv[l]; a.K[l] = Kv[l]; a.Kp[l] = Kp[l];
            a.start[l] = acc0;
            acc0 += Mp[l] * Kp[l];
        }
        a.start[6] = acc0;
        a.maxd2 = maxd2;
        wconv_all_kernel<<<(acc0 + 255) / 256, 256, 0, stream>>>(a);
    }

    // eigen branch
    dim3 gsplit(N_PTS / 64, JS, BATCH);
    radius_max_kernel<<<gsplit, 256, 0, stream>>>(xyz, maxd2);
    eigen_accum_kernel<<<gsplit, 256, 0, stream>>>(xyz, maxd2, pbuf);
    eigen_finalize_kernel<<<(BATCH * N_PTS + 255) / 256, 256, 0, stream>>>(
        xyz, pbuf, ed_w1, ed_b1, ed_w2, ed_b2, zinT, out);

    h1_transpose_kernel<<<dim3(N_PTS / 32, BATCH), 256, 0, stream>>>(h1, zinT);

    // GEMM chain
    // DG1 fused (h2_in f32 direct): 1024 -> 256
    dg1_fused_kernel<<<dim3(N_PTS/64, 4, BATCH), 256, 0, stream>>>(
        wb1, h2_in, dg_b1, dg_s1, dg_t1, bufA);
    // DG2: 256 -> 64
    mfma_gemm<64, 32, true><<<dim3(N_PTS/32, 1, BATCH), 256, 0, stream>>>(
        wb2, bufA, dg_b2, dg_s2, dg_t2, bufC, 64, 256, 64, 0);
    // DG3: 64 -> 32 (zinT ch 128..159)
    mfma_gemm<64, 32, true><<<dim3(N_PTS/32, 1, BATCH), 256, 0, stream>>>(
        wb3, bufC, dg_b3, dg_s3, dg_t3, zinT + 128, 32, 64, 192, 0);
    // F1: 192 -> 512
    mfma_gemm<128, 64, true><<<dim3(N_PTS/64, 4, BATCH), 256, 0, stream>>>(
        wbf1, zinT, b1, s1, t1, bufB, 512, 192, 512, 0);
    // F2: 512 -> 256
    mfma_gemm<64, 64, true><<<dim3(N_PTS/64, 4, BATCH), 256, 0, stream>>>(
        wbf2, bufB, b2, s2, t2, bufD, 256, 512, 256, 0);
    // F3: 256 -> 128 (f32 [b][m][n] into d_out after xyz)
    mfma_gemm<64, 32, false><<<dim3(N_PTS/32, 2, BATCH), 256, 0, stream>>>(
        wbf3, bufD, b3, s3, t3, out + (size_t)BATCH * N_PTS * 3, 128, 256, 0,
        (size_t)128 * N_PTS);
}

// Round 11
// 131.507 us; speedup vs baseline: 1.4469x; 1.0636x over previous
//
#include <hip/hip_runtime.h>
#include <math.h>

#define N_PTS 4096
#define BATCH 4
#define JS 8                  // j-split factor
#define JCH (N_PTS / JS)      // 512 points per j-chunk

typedef short bf16x8 __attribute__((ext_vector_type(8)));
typedef short bf16x4 __attribute__((ext_vector_type(4)));
typedef float f32x4 __attribute__((ext_vector_type(4)));
typedef _Float16 f16x8 __attribute__((ext_vector_type(8)));

// f32 -> fp16 (RNE), bit pattern in short
__device__ inline short f2h(float f) {
    _Float16 h = (_Float16)f;
    return __builtin_bit_cast(short, h);
}

// ---------------------------------------------------------------------------
// Per-batch max pairwise squared distance, TRIANGULAR early-exit.
// Grid: (N/64, JS, B), 256 threads.
// ---------------------------------------------------------------------------
__global__ __launch_bounds__(256) void radius_max_kernel(
    const float* __restrict__ xyz, unsigned int* __restrict__ maxd2)
{
    if ((int)blockIdx.x >= 8 * (int)blockIdx.y + 8) return;   // uniform exit
    const int b = blockIdx.z;
    __shared__ float4 sj[JCH];
    const float* xb = xyz + (size_t)b * N_PTS * 3;
    const int j0 = blockIdx.y * JCH;
    for (int idx = threadIdx.x; idx < JCH; idx += 256) {
        int j = j0 + idx;
        float x = xb[j*3+0], y = xb[j*3+1], z = xb[j*3+2];
        sj[idx] = make_float4(x, y, z, fmaf(x, x, fmaf(y, y, z * z)));
    }
    __syncthreads();
    const int il = threadIdx.x & 63;
    const int jq = threadIdx.x >> 6;
    const int i = blockIdx.x * 64 + il;
    const float xi = xb[i*3+0], yi = xb[i*3+1], zi = xb[i*3+2];
    const float x2i = fmaf(xi, xi, fmaf(yi, yi, zi * zi));
    float m = 0.f;
    const int jb = jq * (JCH / 4);
    #pragma unroll 4
    for (int j = jb; j < jb + JCH / 4; ++j) {
        float4 p = sj[j];
        float dot = fmaf(xi, p.x, fmaf(yi, p.y, zi * p.z));
        float d2 = fmaf(-2.f, dot, x2i + p.w);
        m = fmaxf(m, d2);
    }
    for (int off = 32; off >= 1; off >>= 1) m = fmaxf(m, __shfl_down(m, off));
    __shared__ float wred[4];
    if ((threadIdx.x & 63) == 0) wred[threadIdx.x >> 6] = m;
    __syncthreads();
    if (threadIdx.x == 0) {
        float mm = fmaxf(fmaxf(wred[0], wred[1]), fmaxf(wred[2], wred[3]));
        atomicMax(&maxd2[b], __float_as_uint(mm));
    }
}

// ---------------------------------------------------------------------------
// Eigen accumulate via MFMA (round-9 validated). Grid: (N/64, JS, B).
// ---------------------------------------------------------------------------
__global__ __launch_bounds__(256) void eigen_accum_kernel(
    const float* __restrict__ xyz, const unsigned int* __restrict__ maxd2,
    float* __restrict__ pbuf)
{
    const int b = blockIdx.z, js = blockIdx.y;
    __shared__ __align__(16) float4 sj4[JCH];
    __shared__ __align__(16) _Float16 Ft[16][JCH + 8];
    const float* xb = xyz + (size_t)b * N_PTS * 3;
    const int j0g = js * JCH;
    for (int idx = threadIdx.x; idx < JCH; idx += 256) {
        int j = j0g + idx;
        float x = xb[j*3+0], y = xb[j*3+1], z = xb[j*3+2];
        sj4[idx] = make_float4(x, y, z, fmaf(x, x, fmaf(y, y, z * z)));
        Ft[0][idx] = (_Float16)1.f;
        Ft[1][idx] = (_Float16)x;
        Ft[2][idx] = (_Float16)y;
        Ft[3][idx] = (_Float16)z;
        Ft[4][idx] = (_Float16)(x * x);
        Ft[5][idx] = (_Float16)(x * y);
        Ft[6][idx] = (_Float16)(x * z);
        Ft[7][idx] = (_Float16)(y * y);
        Ft[8][idx] = (_Float16)(y * z);
        Ft[9][idx] = (_Float16)(z * z);
        Ft[10][idx] = (_Float16)0.f; Ft[11][idx] = (_Float16)0.f;
        Ft[12][idx] = (_Float16)0.f; Ft[13][idx] = (_Float16)0.f;
        Ft[14][idx] = (_Float16)0.f; Ft[15][idx] = (_Float16)0.f;
    }
    __syncthreads();

    const int lane = threadIdx.x & 63, wave = threadIdx.x >> 6;
    const int r = lane & 15, g = lane >> 4;
    const int i_wf = blockIdx.x * 64 + wave * 16 + r;
    const float xi = xb[i_wf*3+0], yi = xb[i_wf*3+1], zi = xb[i_wf*3+2];
    const float x2i = fmaf(xi, xi, fmaf(yi, yi, zi * zi));
    const float r2 = 0.01f * __uint_as_float(maxd2[b]);

    f32x4 acc = (f32x4){0.f, 0.f, 0.f, 0.f};
    #pragma unroll 4
    for (int t = 0; t < JCH / 32; ++t) {
        const int jb = t * 32 + g * 8;
        f16x8 wfv;
        #pragma unroll
        for (int s = 0; s < 8; ++s) {
            float4 p = sj4[jb + s];
            float dot = fmaf(xi, p.x, fmaf(yi, p.y, zi * p.z));
            float d2 = fmaf(-2.f, dot, x2i + p.w);
            wfv[s] = (d2 < r2) ? (_Float16)1.f : (_Float16)0.f;
        }
        f16x8 fv = *(const f16x8*)&Ft[r][jb];
        acc = __builtin_amdgcn_mfma_f32_16x16x32_f16(wfv, fv, acc, 0, 0, 0);
    }

    const int i_out = blockIdx.x * 64 + wave * 16 + g * 4;
    float* dst = pbuf + ((size_t)(b * JS + js) * N_PTS + i_out) * 16 + r;
    #pragma unroll
    for (int e = 0; e < 4; ++e) dst[(size_t)e * 16] = acc[e];
}

// ---------------------------------------------------------------------------
// Eigen finalize (+ xyz passthrough). Round-9 validated.
// ---------------------------------------------------------------------------
__global__ __launch_bounds__(256) void eigen_finalize_kernel(
    const float* __restrict__ xyz, const float* __restrict__ pbuf,
    const float* __restrict__ ew1, const float* __restrict__ eb1,
    const float* __restrict__ ew2, const float* __restrict__ eb2,
    short* __restrict__ zinT, float* __restrict__ out)
{
    int id = blockIdx.x * 256 + threadIdx.x;
    if (id >= BATCH * N_PTS) return;
    int b = id >> 12, i = id & (N_PTS - 1);

    out[id*3+0] = xyz[id*3+0];
    out[id*3+1] = xyz[id*3+1];
    out[id*3+2] = xyz[id*3+2];

    double s[10] = {0,0,0,0,0,0,0,0,0,0};
    for (int js = 0; js < JS; ++js) {
        const float* src = pbuf + ((size_t)(b * JS + js) * N_PTS + i) * 16;
        #pragma unroll
        for (int q = 0; q < 10; ++q) s[q] += (double)src[q];
    }
    const float* xb = xyz + (size_t)b * N_PTS * 3;
    float xi = xb[i*3+0], yi = xb[i*3+1], zi = xb[i*3+2];
    s[0] -= 1.0;
    s[1] -= (double)(float)(_Float16)xi;
    s[2] -= (double)(float)(_Float16)yi;
    s[3] -= (double)(float)(_Float16)zi;
    s[4] -= (double)(float)(_Float16)(xi * xi);
    s[5] -= (double)(float)(_Float16)(xi * yi);
    s[6] -= (double)(float)(_Float16)(xi * zi);
    s[7] -= (double)(float)(_Float16)(yi * yi);
    s[8] -= (double)(float)(_Float16)(yi * zi);
    s[9] -= (double)(float)(_Float16)(zi * zi);

    double cnt = s[0];
    double denom = fmax(cnt, 1.0);
    double mx = s[1] / denom, my = s[2] / denom, mz = s[3] / denom;
    const double invN = 1.0 / (double)N_PTS;
    double c00 = (s[4] - cnt * mx * mx) * invN;
    double c01 = (s[5] - cnt * mx * my) * invN;
    double c02 = (s[6] - cnt * mx * mz) * invN;
    double c11 = (s[7] - cnt * my * my) * invN;
    double c12 = (s[8] - cnt * my * mz) * invN;
    double c22 = (s[9] - cnt * mz * mz) * invN;

    double qm = (c00 + c11 + c22) / 3.0;
    double p1 = c01*c01 + c02*c02 + c12*c12;
    double a0 = c00 - qm, a1 = c11 - qm, a2 = c22 - qm;
    double p2 = a0*a0 + a1*a1 + a2*a2 + 2.0*p1;
    double e_lo, e_mid, e_hi;
    if (p2 < 1e-32) {
        e_lo = e_mid = e_hi = qm;
    } else {
        double p = sqrt(p2 / 6.0);
        double inv = 1.0 / p;
        double b00 = a0*inv, b11 = a1*inv, b22 = a2*inv;
        double b01 = c01*inv, b02 = c02*inv, b12 = c12*inv;
        double detB = b00*(b11*b22 - b12*b12)
                    - b01*(b01*b22 - b12*b02)
                    + b02*(b01*b12 - b11*b02);
        double r = 0.5 * detB;
        r = fmin(1.0, fmax(-1.0, r));
        double phi = acos(r) / 3.0;
        double two_p = 2.0 * p;
        e_hi = qm + two_p * cos(phi);
        e_lo = qm + two_p * cos(phi + 2.0943951023931953);
        e_mid = 3.0 * qm - e_hi - e_lo;
    }
    float e0 = (float)e_lo, e1 = (float)e_mid, e2 = (float)e_hi;

    float t[4];
    #pragma unroll
    for (int o = 0; o < 4; ++o)
        t[o] = fmaxf(e0 * ew1[o*3+0] + e1 * ew1[o*3+1] +
                     e2 * ew1[o*3+2] + eb1[o], 0.f);
    bf16x4 ov;
    #pragma unroll
    for (int o = 0; o < 4; ++o) {
        float h = t[0]*ew2[o*4+0] + t[1]*ew2[o*4+1] +
                  t[2]*ew2[o*4+2] + t[3]*ew2[o*4+3] + eb2[o];
        ov[o] = f2h(h);
    }
    *(bf16x4*)&zinT[((size_t)b * N_PTS + i) * 192 + 160] = ov;
}

// ---------------------------------------------------------------------------
// h1 [B][128][N] f32 -> zinT [B][N][192] fp16 ch 0..127, zero ch 164..191.
// ---------------------------------------------------------------------------
__global__ __launch_bounds__(256) void h1_transpose_kernel(
    const float* __restrict__ h1, short* __restrict__ zinT)
{
    const int b = blockIdx.y;
    const int n0 = blockIdx.x * 32;
    __shared__ float tile[128][33];
    #pragma unroll
    for (int it = 0; it < 16; ++it) {
        int idx = it * 256 + threadIdx.x;
        int c = idx >> 5, n = idx & 31;
        tile[c][n] = h1[((size_t)b * 128 + c) * N_PTS + n0 + n];
    }
    __syncthreads();
    #pragma unroll
    for (int it = 0; it < 16; ++it) {
        int idx = it * 256 + threadIdx.x;
        int c = idx & 127, n = idx >> 7;
        zinT[((size_t)b * N_PTS + n0 + n) * 192 + c] = f2h(tile[c][n]);
    }
    for (int idx = threadIdx.x; idx < 32 * 28; idx += 256) {
        int n = idx / 28, c = 164 + idx % 28;
        zinT[((size_t)b * N_PTS + n0 + n) * 192 + c] = 0;
    }
}

// ---------------------------------------------------------------------------
// All 6 weight conversions in ONE kernel (+ maxd2 init in block 0).
// ---------------------------------------------------------------------------
struct WcArgs {
    const float* W[6];
    short* O[6];
    int M[6], K[6], Kp[6];
    int start[7];
    unsigned int* maxd2;
};

__global__ __launch_bounds__(256) void wconv_all_kernel(WcArgs a)
{
    if (blockIdx.x == 0 && threadIdx.x < BATCH) a.maxd2[threadIdx.x] = 0u;
    int id = blockIdx.x * 256 + threadIdx.x;
    if (id >= a.start[6]) return;
    int l = 0;
    #pragma unroll
    for (int q = 1; q < 6; ++q) if (id >= a.start[q]) l = q;
    int local = id - a.start[l];
    int kp = a.Kp[l];
    int mrow = local / kp, k = local - mrow * kp;
    float v = (mrow < a.M[l] && k < a.K[l]) ? a.W[l][(size_t)mrow * a.K[l] + k] : 0.f;
    a.O[l][local] = f2h(v);
}

// ---------------------------------------------------------------------------
// DG1 FUSED v2: reads h2_in [B][1024][N] f32 directly, TRANSPOSE IN REGISTERS
// via the load pattern: wave w, lane tn issues 8 scalar loads
// h2[k0 + w*8 + s][n0 + tn] (each instr = 64 lanes x 4B = 256B coalesced);
// thread then holds k=w*8..w*8+7 of column tn = one bf16x8 Xl row-chunk.
// No tt tile, no second barrier: the exact single-sync pipeline of the
// validated mfma_gemm. BM=128 (grid y=2) halves h2 re-reads and doubles
// MFMA per staging cycle. Out: Y [B][N][256] fp16 (OUTT epilogue).
// ---------------------------------------------------------------------------
__global__ __launch_bounds__(256) void dg1_fused_kernel(
    const short* __restrict__ Wb, const float* __restrict__ h2,
    const float* __restrict__ bias, const float* __restrict__ scale,
    const float* __restrict__ shift, short* __restrict__ Y)
{
    constexpr int LDW = 40;
    constexpr int BM = 128, BN = 64;
    constexpr int NT = 32;                    // K = 1024
    __shared__ __align__(16) short Wl[2][BM][LDW];
    __shared__ __align__(16) short Xl[2][BN][LDW];

    const int tid = threadIdx.x;
    const int lane = tid & 63, wave = tid >> 6;
    const int g = lane >> 4, r = lane & 15;
    const int wr = wave >> 1, wc = wave & 1;
    const int wm0 = wr * 64, wn0 = wc * 32;   // wave-tile 64m x 32n
    const int b = blockIdx.z;
    const int m0 = blockIdx.y * BM, n0 = blockIdx.x * BN;

    const int tn = tid & 63;                  // X: column within n-tile
    const int tw = tid >> 6;                  // X: k-octet = wave index

    f32x4 acc[4][2];
    #pragma unroll
    for (int i = 0; i < 4; ++i)
        #pragma unroll
        for (int j = 0; j < 2; ++j) acc[i][j] = (f32x4){0.f,0.f,0.f,0.f};

    bf16x8 wreg[2];
    float xs[8];

    auto load_regs = [&](int t) {
        #pragma unroll
        for (int u = 0; u < 2; ++u) {
            int id = u * 256 + tid;
            int m = id >> 2, c4 = id & 3;
            wreg[u] = *(const bf16x8*)&Wb[(size_t)(m0 + m) * 1024 + (t << 5) + c4 * 8];
        }
        const float* src = &h2[((size_t)b * 1024 + (t << 5) + tw * 8) * N_PTS + n0 + tn];
        #pragma unroll
        for (int s = 0; s < 8; ++s) xs[s] = src[(size_t)s * N_PTS];
    };
    auto write_lds = [&](int nb) {
        #pragma unroll
        for (int u = 0; u < 2; ++u) {
            int id = u * 256 + tid;
            int m = id >> 2, c4 = id & 3;
            *(bf16x8*)&Wl[nb][m][c4 * 8] = wreg[u];
        }
        bf16x8 v;
        #pragma unroll
        for (int s = 0; s < 8; ++s) v[s] = f2h(xs[s]);
        *(bf16x8*)&Xl[nb][tn][tw * 8] = v;
    };
    auto compute = [&](int cb) {
        #pragma unroll
        for (int fn = 0; fn < 2; ++fn) {
            bf16x8 bb = *(const bf16x8*)&Xl[cb][wn0 + fn * 16 + r][g * 8];
            #pragma unroll
            for (int fm = 0; fm < 4; ++fm) {
                bf16x8 a = *(const bf16x8*)&Wl[cb][wm0 + fm * 16 + r][g * 8];
                acc[fm][fn] = __builtin_amdgcn_mfma_f32_16x16x32_f16(
                    __builtin_bit_cast(f16x8, a),
                    __builtin_bit_cast(f16x8, bb),
                    acc[fm][fn], 0, 0, 0);
            }
        }
    };

    load_regs(0);
    write_lds(0);
    __syncthreads();
    for (int t = 0; t < NT; ++t) {
        int cb = t & 1;
        if (t + 1 < NT) load_regs(t + 1);
        compute(cb);
        if (t + 1 < NT) write_lds(cb ^ 1);
        __syncthreads();
    }

    // epilogue: fp16 transposed out into Y[b][n][256] at channel mb
    #pragma unroll
    for (int fm = 0; fm < 4; ++fm) {
        int mb = m0 + wm0 + fm * 16 + g * 4;
        float4 b4 = *(const float4*)&bias[mb];
        float4 s4 = *(const float4*)&scale[mb];
        float4 h4 = *(const float4*)&shift[mb];
        #pragma unroll
        for (int fn = 0; fn < 2; ++fn) {
            int n = n0 + wn0 + fn * 16 + r;
            f32x4 a = acc[fm][fn];
            bf16x4 o;
            o[0] = f2h(fmaxf(fmaf(a[0] + b4.x, s4.x, h4.x), 0.f));
            o[1] = f2h(fmaxf(fmaf(a[1] + b4.y, s4.y, h4.y), 0.f));
            o[2] = f2h(fmaxf(fmaf(a[2] + b4.z, s4.z, h4.z), 0.f));
            o[3] = f2h(fmaxf(fmaf(a[3] + b4.w, s4.w, h4.w), 0.f));
            *(bf16x4*)&Y[((size_t)b * N_PTS + n) * 256 + mb] = o;
        }
    }
}

// ---------------------------------------------------------------------------
// fp16 MFMA GEMM, k-contiguous X (XT: [B][N][Kp] fp16). Rounds 7-10 validated.
// ---------------------------------------------------------------------------
template<int BM, int BN, bool OUTT>
__global__ __launch_bounds__(256) void mfma_gemm(
    const short* __restrict__ Wb, const short* __restrict__ XT,
    const float* __restrict__ bias, const float* __restrict__ scale,
    const float* __restrict__ shift, void* __restrict__ Yv,
    int M, int Kp, int ostride, size_t ybs)
{
    constexpr int LDW = 40;
    constexpr int FM = BM / 32, FN = BN / 32;
    constexpr int NCH = (BM + BN) * 4;
    constexpr int NREG = (NCH + 255) / 256;
    __shared__ __align__(16) short Wl[2][BM][LDW];
    __shared__ __align__(16) short Xl[2][BN][LDW];

    const int tid = threadIdx.x;
    const int lane = tid & 63, wave = tid >> 6;
    const int g = lane >> 4, r = lane & 15;
    const int wr = wave >> 1, wc = wave & 1;
    const int wm0 = wr * (BM / 2), wn0 = wc * (BN / 2);
    const int b = blockIdx.z;
    const int m0 = blockIdx.y * BM, n0 = blockIdx.x * BN;
    const int NT = Kp >> 5;

    f32x4 acc[FM][FN];
    #pragma unroll
    for (int i = 0; i < FM; ++i)
        #pragma unroll
        for (int jj = 0; jj < FN; ++jj)
            acc[i][jj] = (f32x4){0.f, 0.f, 0.f, 0.f};

    bf16x8 rg[NREG];

    auto load_regs = [&](int t) {
        #pragma unroll
        for (int u = 0; u < NREG; ++u) {
            int id = u * 256 + tid;
            if (id < NCH) {
                if (id < BM * 4) {
                    int m = id >> 2, c4 = id & 3;
                    rg[u] = *(const bf16x8*)&Wb[(size_t)(m0 + m) * Kp + (t << 5) + c4 * 8];
                } else {
                    int id2 = id - BM * 4;
                    int n = id2 >> 2, c4 = id2 & 3;
                    rg[u] = *(const bf16x8*)&XT[((size_t)b * N_PTS + n0 + n) * Kp + (t << 5) + c4 * 8];
                }
            }
        }
    };
    auto write_lds = [&](int nb) {
        #pragma unroll
        for (int u = 0; u < NREG; ++u) {
            int id = u * 256 + tid;
            if (id < NCH) {
                if (id < BM * 4) {
                    int m = id >> 2, c4 = id & 3;
                    *(bf16x8*)&Wl[nb][m][c4 * 8] = rg[u];
                } else {
                    int id2 = id - BM * 4;
                    int n = id2 >> 2, c4 = id2 & 3;
                    *(bf16x8*)&Xl[nb][n][c4 * 8] = rg[u];
                }
            }
        }
    };
    auto compute = [&](int cb) {
        #pragma unroll
        for (int fn = 0; fn < FN; ++fn) {
            bf16x8 bb = *(const bf16x8*)&Xl[cb][wn0 + fn * 16 + r][g * 8];
            #pragma unroll
            for (int fm = 0; fm < FM; ++fm) {
                bf16x8 a = *(const bf16x8*)&Wl[cb][wm0 + fm * 16 + r][g * 8];
                acc[fm][fn] = __builtin_amdgcn_mfma_f32_16x16x32_f16(
                    __builtin_bit_cast(f16x8, a),
                    __builtin_bit_cast(f16x8, bb),
                    acc[fm][fn], 0, 0, 0);
            }
        }
    };

    load_regs(0);
    write_lds(0);
    __syncthreads();
    for (int t = 0; t < NT; ++t) {
        int cb = t & 1;
        if (t + 1 < NT) load_regs(t + 1);
        compute(cb);
        if (t + 1 < NT) write_lds(cb ^ 1);
        __syncthreads();
    }

    if constexpr (OUTT) {
        short* Y = (short*)Yv;
        #pragma unroll
        for (int fm = 0; fm < FM; ++fm) {
            int mb = m0 + wm0 + fm * 16 + g * 4;
            if (mb < M) {
                float4 b4 = *(const float4*)&bias[mb];
                float4 s4 = *(const float4*)&scale[mb];
                float4 h4 = *(const float4*)&shift[mb];
                #pragma unroll
                for (int fn = 0; fn < FN; ++fn) {
                    int n = n0 + wn0 + fn * 16 + r;
                    f32x4 a = acc[fm][fn];
                    bf16x4 o;
                    o[0] = f2h(fmaxf(fmaf(a[0] + b4.x, s4.x, h4.x), 0.f));
                    o[1] = f2h(fmaxf(fmaf(a[1] + b4.y, s4.y, h4.y), 0.f));
                    o[2] = f2h(fmaxf(fmaf(a[2] + b4.z, s4.z, h4.z), 0.f));
                    o[3] = f2h(fmaxf(fmaf(a[3] + b4.w, s4.w, h4.w), 0.f));
                    *(bf16x4*)&Y[((size_t)b * N_PTS + n) * ostride + mb] = o;
                }
            }
        }
    } else {
        float* Y = (float*)Yv;
        #pragma unroll
        for (int fm = 0; fm < FM; ++fm) {
            int mbase = m0 + wm0 + fm * 16 + g * 4;
            #pragma unroll
            for (int e = 0; e < 4; ++e) {
                int mm = mbase + e;
                if (mm >= M) continue;
                float bs = bias[mm], sc = scale[mm], sh = shift[mm];
                #pragma unroll
                for (int fn = 0; fn < FN; ++fn) {
                    int n = n0 + wn0 + fn * 16 + r;
                    float v = fmaxf(fmaf(acc[fm][fn][e] + bs, sc, sh), 0.f);
                    Y[(size_t)b * ybs + (size_t)mm * N_PTS + n] = v;
                }
            }
        }
    }
}

// ---------------------------------------------------------------------------
extern "C" void kernel_launch(void* const* d_in, const int* in_sizes, int n_in,
                              void* d_out, int out_size, void* d_ws, size_t ws_size,
                              hipStream_t stream)
{
    const float* xyz   = (const float*)d_in[0];
    const float* h1    = (const float*)d_in[1];
    const float* h2_in = (const float*)d_in[2];
    const float* dg_w1 = (const float*)d_in[3];
    const float* dg_b1 = (const float*)d_in[4];
    const float* dg_s1 = (const float*)d_in[5];
    const float* dg_t1 = (const float*)d_in[6];
    const float* dg_w2 = (const float*)d_in[7];
    const float* dg_b2 = (const float*)d_in[8];
    const float* dg_s2 = (const float*)d_in[9];
    const float* dg_t2 = (const float*)d_in[10];
    const float* dg_w3 = (const float*)d_in[11];
    const float* dg_b3 = (const float*)d_in[12];
    const float* dg_s3 = (const float*)d_in[13];
    const float* dg_t3 = (const float*)d_in[14];
    const float* ed_w1 = (const float*)d_in[15];
    const float* ed_b1 = (const float*)d_in[16];
    const float* ed_w2 = (const float*)d_in[17];
    const float* ed_b2 = (const float*)d_in[18];
    const float* w1 = (const float*)d_in[19];
    const float* b1 = (const float*)d_in[20];
    const float* s1 = (const float*)d_in[21];
    const float* t1 = (const float*)d_in[22];
    const float* w2 = (const float*)d_in[23];
    const float* b2 = (const float*)d_in[24];
    const float* s2 = (const float*)d_in[25];
    const float* t2 = (const float*)d_in[26];
    const float* w3 = (const float*)d_in[27];
    const float* b3 = (const float*)d_in[28];
    const float* s3 = (const float*)d_in[29];
    const float* t3 = (const float*)d_in[30];

    float* out = (float*)d_out;

    char* ws = (char*)d_ws;
    size_t off = 0;
    auto alloc = [&](size_t bytes) {
        char* p = ws + off;
        off += (bytes + 255) & ~(size_t)255;
        return p;
    };
    unsigned int* maxd2 = (unsigned int*)alloc(256);
    short* wb1  = (short*)alloc((size_t)256 * 1024 * 2);
    short* wb2  = (short*)alloc((size_t)64  * 256  * 2);
    short* wb3  = (short*)alloc((size_t)64  * 64   * 2);
    short* wbf1 = (short*)alloc((size_t)512 * 192  * 2);
    short* wbf2 = (short*)alloc((size_t)256 * 512  * 2);
    short* wbf3 = (short*)alloc((size_t)128 * 256  * 2);
    short* zinT = (short*)alloc((size_t)BATCH * N_PTS * 192 * 2);   // 6.3 MB
    short* bufA = (short*)alloc((size_t)BATCH * N_PTS * 256 * 2);   // 8.4 MB
    short* bufB = (short*)alloc((size_t)BATCH * N_PTS * 512 * 2);   // 16.8 MB
    short* bufC = (short*)alloc((size_t)BATCH * N_PTS * 64 * 2);    // 2.1 MB
    float* pbuf = (float*)alloc((size_t)BATCH * JS * N_PTS * 16 * 4); // 8.4 MB
    short* bufD = bufA;   // [B][N][256] fp16 (bufA dead after DG2)

    // all weight conversions + maxd2 init in one launch
    {
        WcArgs a;
        const float* Wp[6] = {dg_w1, dg_w2, dg_w3, w1, w2, w3};
        short* Op[6] = {wb1, wb2, wb3, wbf1, wbf2, wbf3};
        int Mv[6] = {256, 64, 32, 512, 256, 128};
        int Kv[6] = {1024, 256, 64, 164, 512, 256};
        int Mp[6] = {256, 64, 64, 512, 256, 128};
        int Kp[6] = {1024, 256, 64, 192, 512, 256};
        int acc0 = 0;
        for (int l = 0; l < 6; ++l) {
            a.W[l] = Wp[l]; a.O[l] = Op[l];
            a.M[l] = Mv[l]; a.K[l] = Kv[l]; a.Kp[l] = Kp[l];
            a.start[l] = acc0;
            acc0 += Mp[l] * Kp[l];
        }
        a.start[6] = acc0;
        a.maxd2 = maxd2;
        wconv_all_kernel<<<(acc0 + 255) / 256, 256, 0, stream>>>(a);
    }

    // eigen branch
    dim3 gsplit(N_PTS / 64, JS, BATCH);
    radius_max_kernel<<<gsplit, 256, 0, stream>>>(xyz, maxd2);
    eigen_accum_kernel<<<gsplit, 256, 0, stream>>>(xyz, maxd2, pbuf);
    eigen_finalize_kernel<<<(BATCH * N_PTS + 255) / 256, 256, 0, stream>>>(
        xyz, pbuf, ed_w1, ed_b1, ed_w2, ed_b2, zinT, out);

    h1_transpose_kernel<<<dim3(N_PTS / 32, BATCH), 256, 0, stream>>>(h1, zinT);

    // GEMM chain
    // DG1 fused v2 (h2_in f32 direct, register transpose): 1024 -> 256
    dg1_fused_kernel<<<dim3(N_PTS/64, 2, BATCH), 256, 0, stream>>>(
        wb1, h2_in, dg_b1, dg_s1, dg_t1, bufA);
    // DG2: 256 -> 64
    mfma_gemm<64, 32, true><<<dim3(N_PTS/32, 1, BATCH), 256, 0, stream>>>(
        wb2, bufA, dg_b2, dg_s2, dg_t2, bufC, 64, 256, 64, 0);
    // DG3: 64 -> 32 (zinT ch 128..159)
    mfma_gemm<64, 32, true><<<dim3(N_PTS/32, 1, BATCH), 256, 0, stream>>>(
        wb3, bufC, dg_b3, dg_s3, dg_t3, zinT + 128, 32, 64, 192, 0);
    // F1: 192 -> 512
    mfma_gemm<128, 64, true><<<dim3(N_PTS/64, 4, BATCH), 256, 0, stream>>>(
        wbf1, zinT, b1, s1, t1, bufB, 512, 192, 512, 0);
    // F2: 512 -> 256
    mfma_gemm<64, 64, true><<<dim3(N_PTS/64, 4, BATCH), 256, 0, stream>>>(
        wbf2, bufB, b2, s2, t2, bufD, 256, 512, 256, 0);
    // F3: 256 -> 128 (f32 [b][m][n] into d_out after xyz)
    mfma_gemm<64, 32, false><<<dim3(N_PTS/32, 2, BATCH), 256, 0, stream>>>(
        wbf3, bufD, b3, s3, t3, out + (size_t)BATCH * N_PTS * 3, 128, 256, 0,
        (size_t)128 * N_PTS);
}

// Round 12
// 131.481 us; speedup vs baseline: 1.4472x; 1.0002x over previous
//
#include <hip/hip_runtime.h>
#include <math.h>

#define N_PTS 4096
#define BATCH 4
#define JS 8                  // j-split factor
#define JCH (N_PTS / JS)      // 512 points per j-chunk

typedef short bf16x8 __attribute__((ext_vector_type(8)));
typedef short bf16x4 __attribute__((ext_vector_type(4)));
typedef float f32x4 __attribute__((ext_vector_type(4)));
typedef _Float16 f16x8 __attribute__((ext_vector_type(8)));

// f32 -> fp16 (RNE), bit pattern in short
__device__ inline short f2h(float f) {
    _Float16 h = (_Float16)f;
    return __builtin_bit_cast(short, h);
}

// ---------------------------------------------------------------------------
// Per-batch max pairwise squared distance, TRIANGULAR early-exit.
// Grid: (N/64, JS, B), 256 threads.
// ---------------------------------------------------------------------------
__global__ __launch_bounds__(256) void radius_max_kernel(
    const float* __restrict__ xyz, unsigned int* __restrict__ maxd2)
{
    if ((int)blockIdx.x >= 8 * (int)blockIdx.y + 8) return;   // uniform exit
    const int b = blockIdx.z;
    __shared__ float4 sj[JCH];
    const float* xb = xyz + (size_t)b * N_PTS * 3;
    const int j0 = blockIdx.y * JCH;
    for (int idx = threadIdx.x; idx < JCH; idx += 256) {
        int j = j0 + idx;
        float x = xb[j*3+0], y = xb[j*3+1], z = xb[j*3+2];
        sj[idx] = make_float4(x, y, z, fmaf(x, x, fmaf(y, y, z * z)));
    }
    __syncthreads();
    const int il = threadIdx.x & 63;
    const int jq = threadIdx.x >> 6;
    const int i = blockIdx.x * 64 + il;
    const float xi = xb[i*3+0], yi = xb[i*3+1], zi = xb[i*3+2];
    const float x2i = fmaf(xi, xi, fmaf(yi, yi, zi * zi));
    float m = 0.f;
    const int jb = jq * (JCH / 4);
    #pragma unroll 4
    for (int j = jb; j < jb + JCH / 4; ++j) {
        float4 p = sj[j];
        float dot = fmaf(xi, p.x, fmaf(yi, p.y, zi * p.z));
        float d2 = fmaf(-2.f, dot, x2i + p.w);
        m = fmaxf(m, d2);
    }
    for (int off = 32; off >= 1; off >>= 1) m = fmaxf(m, __shfl_down(m, off));
    __shared__ float wred[4];
    if ((threadIdx.x & 63) == 0) wred[threadIdx.x >> 6] = m;
    __syncthreads();
    if (threadIdx.x == 0) {
        float mm = fmaxf(fmaxf(wred[0], wred[1]), fmaxf(wred[2], wred[3]));
        atomicMax(&maxd2[b], __float_as_uint(mm));
    }
}

// ---------------------------------------------------------------------------
// Eigen accumulate via MFMA (round-9 validated). Grid: (N/64, JS, B).
// ---------------------------------------------------------------------------
__global__ __launch_bounds__(256) void eigen_accum_kernel(
    const float* __restrict__ xyz, const unsigned int* __restrict__ maxd2,
    float* __restrict__ pbuf)
{
    const int b = blockIdx.z, js = blockIdx.y;
    __shared__ __align__(16) float4 sj4[JCH];
    __shared__ __align__(16) _Float16 Ft[16][JCH + 8];
    const float* xb = xyz + (size_t)b * N_PTS * 3;
    const int j0g = js * JCH;
    for (int idx = threadIdx.x; idx < JCH; idx += 256) {
        int j = j0g + idx;
        float x = xb[j*3+0], y = xb[j*3+1], z = xb[j*3+2];
        sj4[idx] = make_float4(x, y, z, fmaf(x, x, fmaf(y, y, z * z)));
        Ft[0][idx] = (_Float16)1.f;
        Ft[1][idx] = (_Float16)x;
        Ft[2][idx] = (_Float16)y;
        Ft[3][idx] = (_Float16)z;
        Ft[4][idx] = (_Float16)(x * x);
        Ft[5][idx] = (_Float16)(x * y);
        Ft[6][idx] = (_Float16)(x * z);
        Ft[7][idx] = (_Float16)(y * y);
        Ft[8][idx] = (_Float16)(y * z);
        Ft[9][idx] = (_Float16)(z * z);
        Ft[10][idx] = (_Float16)0.f; Ft[11][idx] = (_Float16)0.f;
        Ft[12][idx] = (_Float16)0.f; Ft[13][idx] = (_Float16)0.f;
        Ft[14][idx] = (_Float16)0.f; Ft[15][idx] = (_Float16)0.f;
    }
    __syncthreads();

    const int lane = threadIdx.x & 63, wave = threadIdx.x >> 6;
    const int r = lane & 15, g = lane >> 4;
    const int i_wf = blockIdx.x * 64 + wave * 16 + r;
    const float xi = xb[i_wf*3+0], yi = xb[i_wf*3+1], zi = xb[i_wf*3+2];
    const float x2i = fmaf(xi, xi, fmaf(yi, yi, zi * zi));
    const float r2 = 0.01f * __uint_as_float(maxd2[b]);

    f32x4 acc = (f32x4){0.f, 0.f, 0.f, 0.f};
    #pragma unroll 4
    for (int t = 0; t < JCH / 32; ++t) {
        const int jb = t * 32 + g * 8;
        f16x8 wfv;
        #pragma unroll
        for (int s = 0; s < 8; ++s) {
            float4 p = sj4[jb + s];
            float dot = fmaf(xi, p.x, fmaf(yi, p.y, zi * p.z));
            float d2 = fmaf(-2.f, dot, x2i + p.w);
            wfv[s] = (d2 < r2) ? (_Float16)1.f : (_Float16)0.f;
        }
        f16x8 fv = *(const f16x8*)&Ft[r][jb];
        acc = __builtin_amdgcn_mfma_f32_16x16x32_f16(wfv, fv, acc, 0, 0, 0);
    }

    const int i_out = blockIdx.x * 64 + wave * 16 + g * 4;
    float* dst = pbuf + ((size_t)(b * JS + js) * N_PTS + i_out) * 16 + r;
    #pragma unroll
    for (int e = 0; e < 4; ++e) dst[(size_t)e * 16] = acc[e];
}

// ---------------------------------------------------------------------------
// Eigen finalize (+ xyz passthrough). Round-9 validated.
// ---------------------------------------------------------------------------
__global__ __launch_bounds__(256) void eigen_finalize_kernel(
    const float* __restrict__ xyz, const float* __restrict__ pbuf,
    const float* __restrict__ ew1, const float* __restrict__ eb1,
    const float* __restrict__ ew2, const float* __restrict__ eb2,
    short* __restrict__ zinT, float* __restrict__ out)
{
    int id = blockIdx.x * 256 + threadIdx.x;
    if (id >= BATCH * N_PTS) return;
    int b = id >> 12, i = id & (N_PTS - 1);

    out[id*3+0] = xyz[id*3+0];
    out[id*3+1] = xyz[id*3+1];
    out[id*3+2] = xyz[id*3+2];

    double s[10] = {0,0,0,0,0,0,0,0,0,0};
    for (int js = 0; js < JS; ++js) {
        const float* src = pbuf + ((size_t)(b * JS + js) * N_PTS + i) * 16;
        #pragma unroll
        for (int q = 0; q < 10; ++q) s[q] += (double)src[q];
    }
    const float* xb = xyz + (size_t)b * N_PTS * 3;
    float xi = xb[i*3+0], yi = xb[i*3+1], zi = xb[i*3+2];
    s[0] -= 1.0;
    s[1] -= (double)(float)(_Float16)xi;
    s[2] -= (double)(float)(_Float16)yi;
    s[3] -= (double)(float)(_Float16)zi;
    s[4] -= (double)(float)(_Float16)(xi * xi);
    s[5] -= (double)(float)(_Float16)(xi * yi);
    s[6] -= (double)(float)(_Float16)(xi * zi);
    s[7] -= (double)(float)(_Float16)(yi * yi);
    s[8] -= (double)(float)(_Float16)(yi * zi);
    s[9] -= (double)(float)(_Float16)(zi * zi);

    double cnt = s[0];
    double denom = fmax(cnt, 1.0);
    double mx = s[1] / denom, my = s[2] / denom, mz = s[3] / denom;
    const double invN = 1.0 / (double)N_PTS;
    double c00 = (s[4] - cnt * mx * mx) * invN;
    double c01 = (s[5] - cnt * mx * my) * invN;
    double c02 = (s[6] - cnt * mx * mz) * invN;
    double c11 = (s[7] - cnt * my * my) * invN;
    double c12 = (s[8] - cnt * my * mz) * invN;
    double c22 = (s[9] - cnt * mz * mz) * invN;

    double qm = (c00 + c11 + c22) / 3.0;
    double p1 = c01*c01 + c02*c02 + c12*c12;
    double a0 = c00 - qm, a1 = c11 - qm, a2 = c22 - qm;
    double p2 = a0*a0 + a1*a1 + a2*a2 + 2.0*p1;
    double e_lo, e_mid, e_hi;
    if (p2 < 1e-32) {
        e_lo = e_mid = e_hi = qm;
    } else {
        double p = sqrt(p2 / 6.0);
        double inv = 1.0 / p;
        double b00 = a0*inv, b11 = a1*inv, b22 = a2*inv;
        double b01 = c01*inv, b02 = c02*inv, b12 = c12*inv;
        double detB = b00*(b11*b22 - b12*b12)
                    - b01*(b01*b22 - b12*b02)
                    + b02*(b01*b12 - b11*b02);
        double r = 0.5 * detB;
        r = fmin(1.0, fmax(-1.0, r));
        double phi = acos(r) / 3.0;
        double two_p = 2.0 * p;
        e_hi = qm + two_p * cos(phi);
        e_lo = qm + two_p * cos(phi + 2.0943951023931953);
        e_mid = 3.0 * qm - e_hi - e_lo;
    }
    float e0 = (float)e_lo, e1 = (float)e_mid, e2 = (float)e_hi;

    float t[4];
    #pragma unroll
    for (int o = 0; o < 4; ++o)
        t[o] = fmaxf(e0 * ew1[o*3+0] + e1 * ew1[o*3+1] +
                     e2 * ew1[o*3+2] + eb1[o], 0.f);
    bf16x4 ov;
    #pragma unroll
    for (int o = 0; o < 4; ++o) {
        float h = t[0]*ew2[o*4+0] + t[1]*ew2[o*4+1] +
                  t[2]*ew2[o*4+2] + t[3]*ew2[o*4+3] + eb2[o];
        ov[o] = f2h(h);
    }
    *(bf16x4*)&zinT[((size_t)b * N_PTS + i) * 192 + 160] = ov;
}

// ---------------------------------------------------------------------------
// h1 [B][128][N] f32 -> zinT [B][N][192] fp16 ch 0..127, zero ch 164..191.
// ---------------------------------------------------------------------------
__global__ __launch_bounds__(256) void h1_transpose_kernel(
    const float* __restrict__ h1, short* __restrict__ zinT)
{
    const int b = blockIdx.y;
    const int n0 = blockIdx.x * 32;
    __shared__ float tile[128][33];
    #pragma unroll
    for (int it = 0; it < 16; ++it) {
        int idx = it * 256 + threadIdx.x;
        int c = idx >> 5, n = idx & 31;
        tile[c][n] = h1[((size_t)b * 128 + c) * N_PTS + n0 + n];
    }
    __syncthreads();
    #pragma unroll
    for (int it = 0; it < 16; ++it) {
        int idx = it * 256 + threadIdx.x;
        int c = idx & 127, n = idx >> 7;
        zinT[((size_t)b * N_PTS + n0 + n) * 192 + c] = f2h(tile[c][n]);
    }
    for (int idx = threadIdx.x; idx < 32 * 28; idx += 256) {
        int n = idx / 28, c = 164 + idx % 28;
        zinT[((size_t)b * N_PTS + n0 + n) * 192 + c] = 0;
    }
}

// ---------------------------------------------------------------------------
// All 6 weight conversions in ONE kernel (+ maxd2 init in block 0).
// ---------------------------------------------------------------------------
struct WcArgs {
    const float* W[6];
    short* O[6];
    int M[6], K[6], Kp[6];
    int start[7];
    unsigned int* maxd2;
};

__global__ __launch_bounds__(256) void wconv_all_kernel(WcArgs a)
{
    if (blockIdx.x == 0 && threadIdx.x < BATCH) a.maxd2[threadIdx.x] = 0u;
    int id = blockIdx.x * 256 + threadIdx.x;
    if (id >= a.start[6]) return;
    int l = 0;
    #pragma unroll
    for (int q = 1; q < 6; ++q) if (id >= a.start[q]) l = q;
    int local = id - a.start[l];
    int kp = a.Kp[l];
    int mrow = local / kp, k = local - mrow * kp;
    float v = (mrow < a.M[l] && k < a.K[l]) ? a.W[l][(size_t)mrow * a.K[l] + k] : 0.f;
    a.O[l][local] = f2h(v);
}

// ---------------------------------------------------------------------------
// DG1 SPLIT-K: grid (64, 2, B*2). Slice ks covers k = ks*512 .. +512.
// Register-transpose X load (validated r11); X LDS tile stride 64 shorts
// (128B) with XOR chunk swizzle: write chunk = tw ^ (tn&7), read chunk =
// g ^ (r&7) (col&7==r&7 since wn0, fn*16 are multiples of 8) -> even 8x8
// quad-bank pattern on both sides (minimum time, no extra conflicts).
// Epilogue: RAW f32 accumulators to part[ks][b][n][256] (no activation).
// 4 blocks/CU (LDS 36.8KB), 16 waves/CU.
// ---------------------------------------------------------------------------
__global__ __launch_bounds__(256) void dg1_splitk_kernel(
    const short* __restrict__ Wb, const float* __restrict__ h2,
    float* __restrict__ part)
{
    constexpr int LDWW = 40;                  // W stride (shorts)
    constexpr int LDX = 64;                   // X stride (shorts), 128B
    constexpr int BM = 128, BN = 64;
    constexpr int NT = 16;                    // K-half = 512
    __shared__ __align__(16) short Wl[2][BM][LDWW];
    __shared__ __align__(16) short Xl[2][BN][LDX];

    const int tid = threadIdx.x;
    const int lane = tid & 63, wave = tid >> 6;
    const int g = lane >> 4, r = lane & 15;
    const int wr = wave >> 1, wc = wave & 1;
    const int wm0 = wr * 64, wn0 = wc * 32;   // wave-tile 64m x 32n
    const int bz = blockIdx.z;
    const int b = bz >> 1, ks = bz & 1;
    const int k0 = ks * 512;
    const int m0 = blockIdx.y * BM, n0 = blockIdx.x * BN;

    const int tn = tid & 63;                  // X: column within n-tile
    const int tw = tid >> 6;                  // X: k-octet = wave index
    const int xchunk = (tw ^ (tn & 7)) * 8;   // swizzled write chunk

    f32x4 acc[4][2];
    #pragma unroll
    for (int i = 0; i < 4; ++i)
        #pragma unroll
        for (int j = 0; j < 2; ++j) acc[i][j] = (f32x4){0.f,0.f,0.f,0.f};

    bf16x8 wreg[2];
    float xs[8];

    auto load_regs = [&](int t) {
        #pragma unroll
        for (int u = 0; u < 2; ++u) {
            int id = u * 256 + tid;
            int m = id >> 2, c4 = id & 3;
            wreg[u] = *(const bf16x8*)&Wb[(size_t)(m0 + m) * 1024 + k0 + (t << 5) + c4 * 8];
        }
        const float* src = &h2[((size_t)b * 1024 + k0 + (t << 5) + tw * 8) * N_PTS + n0 + tn];
        #pragma unroll
        for (int s = 0; s < 8; ++s) xs[s] = src[(size_t)s * N_PTS];
    };
    auto write_lds = [&](int nb) {
        #pragma unroll
        for (int u = 0; u < 2; ++u) {
            int id = u * 256 + tid;
            int m = id >> 2, c4 = id & 3;
            *(bf16x8*)&Wl[nb][m][c4 * 8] = wreg[u];
        }
        bf16x8 v;
        #pragma unroll
        for (int s = 0; s < 8; ++s) v[s] = f2h(xs[s]);
        *(bf16x8*)&Xl[nb][tn][xchunk] = v;
    };
    auto compute = [&](int cb) {
        #pragma unroll
        for (int fn = 0; fn < 2; ++fn) {
            int col = wn0 + fn * 16 + r;
            bf16x8 bb = *(const bf16x8*)&Xl[cb][col][(g ^ (r & 7)) * 8];
            #pragma unroll
            for (int fm = 0; fm < 4; ++fm) {
                bf16x8 a = *(const bf16x8*)&Wl[cb][wm0 + fm * 16 + r][g * 8];
                acc[fm][fn] = __builtin_amdgcn_mfma_f32_16x16x32_f16(
                    __builtin_bit_cast(f16x8, a),
                    __builtin_bit_cast(f16x8, bb),
                    acc[fm][fn], 0, 0, 0);
            }
        }
    };

    load_regs(0);
    write_lds(0);
    __syncthreads();
    for (int t = 0; t < NT; ++t) {
        int cb = t & 1;
        if (t + 1 < NT) load_regs(t + 1);
        compute(cb);
        if (t + 1 < NT) write_lds(cb ^ 1);
        __syncthreads();
    }

    // epilogue: raw f32x4 into part[ks][b][n][256] at channel mb
    float* pbase = part + ((size_t)(ks * BATCH + b) * N_PTS) * 256;
    #pragma unroll
    for (int fm = 0; fm < 4; ++fm) {
        int mb = m0 + wm0 + fm * 16 + g * 4;
        #pragma unroll
        for (int fn = 0; fn < 2; ++fn) {
            int n = n0 + wn0 + fn * 16 + r;
            *(f32x4*)&pbase[(size_t)n * 256 + mb] = acc[fm][fn];
        }
    }
}

// ---------------------------------------------------------------------------
// DG2 FUSED COMBINE: X staging sums the two DG1 k-slice partials, applies
// DG1's bias/BN/ReLU (per-channel k), cvt fp16 -> standard Xl layout.
// Identical single-barrier MFMA pipeline. BM=64 (=M, grid y=1), BN=32, K=256.
// Out: bufC [B][N][64] fp16 with DG2's own activation epilogue.
// ---------------------------------------------------------------------------
__global__ __launch_bounds__(256) void dg2_fused_kernel(
    const short* __restrict__ W2, const float* __restrict__ part,
    const float* __restrict__ cb1, const float* __restrict__ cs1,
    const float* __restrict__ ct1,
    const float* __restrict__ bias, const float* __restrict__ scale,
    const float* __restrict__ shift, short* __restrict__ Y)
{
    constexpr int LDW = 40;
    constexpr int BM = 64, BN = 32, NT = 8;   // K = 256
    __shared__ __align__(16) short Wl[2][BM][LDW];
    __shared__ __align__(16) short Xl[2][BN][LDW];

    const int tid = threadIdx.x;
    const int lane = tid & 63, wave = tid >> 6;
    const int g = lane >> 4, r = lane & 15;
    const int wr = wave >> 1, wc = wave & 1;
    const int wm0 = wr * 32, wn0 = wc * 16;
    const int b = blockIdx.z;
    const int n0 = blockIdx.x * BN;
    const size_t slice = (size_t)BATCH * N_PTS * 256;

    const int xm = tid >> 2, xc4 = tid & 3;   // W chunk (all 256 threads)
    const int xn = tid >> 2;                  // X: n (threads 0..127)

    f32x4 acc[2][1];
    acc[0][0] = (f32x4){0.f,0.f,0.f,0.f};
    acc[1][0] = (f32x4){0.f,0.f,0.f,0.f};

    bf16x8 wreg;
    float4 q0, q1, q2, q3, pb0, pb1, ps0, ps1, pt0, pt1;

    auto load_regs = [&](int t) {
        wreg = *(const bf16x8*)&W2[(size_t)xm * 256 + (t << 5) + xc4 * 8];
        if (tid < 128) {
            int kc = (t << 5) + xc4 * 8;
            const float* p = &part[((size_t)b * N_PTS + n0 + xn) * 256 + kc];
            q0 = *(const float4*)p;       q1 = *(const float4*)(p + 4);
            q2 = *(const float4*)(p + slice); q3 = *(const float4*)(p + slice + 4);
            pb0 = *(const float4*)&cb1[kc]; pb1 = *(const float4*)&cb1[kc + 4];
            ps0 = *(const float4*)&cs1[kc]; ps1 = *(const float4*)&cs1[kc + 4];
            pt0 = *(const float4*)&ct1[kc]; pt1 = *(const float4*)&ct1[kc + 4];
        }
    };
    auto write_lds = [&](int nb) {
        *(bf16x8*)&Wl[nb][xm][xc4 * 8] = wreg;
        if (tid < 128) {
            bf16x8 v;
            v[0] = f2h(fmaxf(fmaf(q0.x + q2.x + pb0.x, ps0.x, pt0.x), 0.f));
            v[1] = f2h(fmaxf(fmaf(q0.y + q2.y + pb0.y, ps0.y, pt0.y), 0.f));
            v[2] = f2h(fmaxf(fmaf(q0.z + q2.z + pb0.z, ps0.z, pt0.z), 0.f));
            v[3] = f2h(fmaxf(fmaf(q0.w + q2.w + pb0.w, ps0.w, pt0.w), 0.f));
            v[4] = f2h(fmaxf(fmaf(q1.x + q3.x + pb1.x, ps1.x, pt1.x), 0.f));
            v[5] = f2h(fmaxf(fmaf(q1.y + q3.y + pb1.y, ps1.y, pt1.y), 0.f));
            v[6] = f2h(fmaxf(fmaf(q1.z + q3.z + pb1.z, ps1.z, pt1.z), 0.f));
            v[7] = f2h(fmaxf(fmaf(q1.w + q3.w + pb1.w, ps1.w, pt1.w), 0.f));
            *(bf16x8*)&Xl[nb][xn][xc4 * 8] = v;
        }
    };
    auto compute = [&](int cb) {
        bf16x8 bb = *(const bf16x8*)&Xl[cb][wn0 + r][g * 8];
        #pragma unroll
        for (int fm = 0; fm < 2; ++fm) {
            bf16x8 a = *(const bf16x8*)&Wl[cb][wm0 + fm * 16 + r][g * 8];
            acc[fm][0] = __builtin_amdgcn_mfma_f32_16x16x32_f16(
                __builtin_bit_cast(f16x8, a),
                __builtin_bit_cast(f16x8, bb),
                acc[fm][0], 0, 0, 0);
        }
    };

    load_regs(0);
    write_lds(0);
    __syncthreads();
    for (int t = 0; t < NT; ++t) {
        int cbuf = t & 1;
        if (t + 1 < NT) load_regs(t + 1);
        compute(cbuf);
        if (t + 1 < NT) write_lds(cbuf ^ 1);
        __syncthreads();
    }

    #pragma unroll
    for (int fm = 0; fm < 2; ++fm) {
        int mb = wm0 + fm * 16 + g * 4;
        float4 b4 = *(const float4*)&bias[mb];
        float4 s4 = *(const float4*)&scale[mb];
        float4 h4 = *(const float4*)&shift[mb];
        int n = n0 + wn0 + r;
        f32x4 a = acc[fm][0];
        bf16x4 o;
        o[0] = f2h(fmaxf(fmaf(a[0] + b4.x, s4.x, h4.x), 0.f));
        o[1] = f2h(fmaxf(fmaf(a[1] + b4.y, s4.y, h4.y), 0.f));
        o[2] = f2h(fmaxf(fmaf(a[2] + b4.z, s4.z, h4.z), 0.f));
        o[3] = f2h(fmaxf(fmaf(a[3] + b4.w, s4.w, h4.w), 0.f));
        *(bf16x4*)&Y[((size_t)b * N_PTS + n) * 64 + mb] = o;
    }
}

// ---------------------------------------------------------------------------
// fp16 MFMA GEMM, k-contiguous X (XT: [B][N][Kp] fp16). Rounds 7-11 validated.
// ---------------------------------------------------------------------------
template<int BM, int BN, bool OUTT>
__global__ __launch_bounds__(256) void mfma_gemm(
    const short* __restrict__ Wb, const short* __restrict__ XT,
    const float* __restrict__ bias, const float* __restrict__ scale,
    const float* __restrict__ shift, void* __restrict__ Yv,
    int M, int Kp, int ostride, size_t ybs)
{
    constexpr int LDW = 40;
    constexpr int FM = BM / 32, FN = BN / 32;
    constexpr int NCH = (BM + BN) * 4;
    constexpr int NREG = (NCH + 255) / 256;
    __shared__ __align__(16) short Wl[2][BM][LDW];
    __shared__ __align__(16) short Xl[2][BN][LDW];

    const int tid = threadIdx.x;
    const int lane = tid & 63, wave = tid >> 6;
    const int g = lane >> 4, r = lane & 15;
    const int wr = wave >> 1, wc = wave & 1;
    const int wm0 = wr * (BM / 2), wn0 = wc * (BN / 2);
    const int b = blockIdx.z;
    const int m0 = blockIdx.y * BM, n0 = blockIdx.x * BN;
    const int NT = Kp >> 5;

    f32x4 acc[FM][FN];
    #pragma unroll
    for (int i = 0; i < FM; ++i)
        #pragma unroll
        for (int jj = 0; jj < FN; ++jj)
            acc[i][jj] = (f32x4){0.f, 0.f, 0.f, 0.f};

    bf16x8 rg[NREG];

    auto load_regs = [&](int t) {
        #pragma unroll
        for (int u = 0; u < NREG; ++u) {
            int id = u * 256 + tid;
            if (id < NCH) {
                if (id < BM * 4) {
                    int m = id >> 2, c4 = id & 3;
                    rg[u] = *(const bf16x8*)&Wb[(size_t)(m0 + m) * Kp + (t << 5) + c4 * 8];
                } else {
                    int id2 = id - BM * 4;
                    int n = id2 >> 2, c4 = id2 & 3;
                    rg[u] = *(const bf16x8*)&XT[((size_t)b * N_PTS + n0 + n) * Kp + (t << 5) + c4 * 8];
                }
            }
        }
    };
    auto write_lds = [&](int nb) {
        #pragma unroll
        for (int u = 0; u < NREG; ++u) {
            int id = u * 256 + tid;
            if (id < NCH) {
                if (id < BM * 4) {
                    int m = id >> 2, c4 = id & 3;
                    *(bf16x8*)&Wl[nb][m][c4 * 8] = rg[u];
                } else {
                    int id2 = id - BM * 4;
                    int n = id2 >> 2, c4 = id2 & 3;
                    *(bf16x8*)&Xl[nb][n][c4 * 8] = rg[u];
                }
            }
        }
    };
    auto compute = [&](int cb) {
        #pragma unroll
        for (int fn = 0; fn < FN; ++fn) {
            bf16x8 bb = *(const bf16x8*)&Xl[cb][wn0 + fn * 16 + r][g * 8];
            #pragma unroll
            for (int fm = 0; fm < FM; ++fm) {
                bf16x8 a = *(const bf16x8*)&Wl[cb][wm0 + fm * 16 + r][g * 8];
                acc[fm][fn] = __builtin_amdgcn_mfma_f32_16x16x32_f16(
                    __builtin_bit_cast(f16x8, a),
                    __builtin_bit_cast(f16x8, bb),
                    acc[fm][fn], 0, 0, 0);
            }
        }
    };

    load_regs(0);
    write_lds(0);
    __syncthreads();
    for (int t = 0; t < NT; ++t) {
        int cb = t & 1;
        if (t + 1 < NT) load_regs(t + 1);
        compute(cb);
        if (t + 1 < NT) write_lds(cb ^ 1);
        __syncthreads();
    }

    if constexpr (OUTT) {
        short* Y = (short*)Yv;
        #pragma unroll
        for (int fm = 0; fm < FM; ++fm) {
            int mb = m0 + wm0 + fm * 16 + g * 4;
            if (mb < M) {
                float4 b4 = *(const float4*)&bias[mb];
                float4 s4 = *(const float4*)&scale[mb];
                float4 h4 = *(const float4*)&shift[mb];
                #pragma unroll
                for (int fn = 0; fn < FN; ++fn) {
                    int n = n0 + wn0 + fn * 16 + r;
                    f32x4 a = acc[fm][fn];
                    bf16x4 o;
                    o[0] = f2h(fmaxf(fmaf(a[0] + b4.x, s4.x, h4.x), 0.f));
                    o[1] = f2h(fmaxf(fmaf(a[1] + b4.y, s4.y, h4.y), 0.f));
                    o[2] = f2h(fmaxf(fmaf(a[2] + b4.z, s4.z, h4.z), 0.f));
                    o[3] = f2h(fmaxf(fmaf(a[3] + b4.w, s4.w, h4.w), 0.f));
                    *(bf16x4*)&Y[((size_t)b * N_PTS + n) * ostride + mb] = o;
                }
            }
        }
    } else {
        float* Y = (float*)Yv;
        #pragma unroll
        for (int fm = 0; fm < FM; ++fm) {
            int mbase = m0 + wm0 + fm * 16 + g * 4;
            #pragma unroll
            for (int e = 0; e < 4; ++e) {
                int mm = mbase + e;
                if (mm >= M) continue;
                float bs = bias[mm], sc = scale[mm], sh = shift[mm];
                #pragma unroll
                for (int fn = 0; fn < FN; ++fn) {
                    int n = n0 + wn0 + fn * 16 + r;
                    float v = fmaxf(fmaf(acc[fm][fn][e] + bs, sc, sh), 0.f);
                    Y[(size_t)b * ybs + (size_t)mm * N_PTS + n] = v;
                }
            }
        }
    }
}

// ---------------------------------------------------------------------------
extern "C" void kernel_launch(void* const* d_in, const int* in_sizes, int n_in,
                              void* d_out, int out_size, void* d_ws, size_t ws_size,
                              hipStream_t stream)
{
    const float* xyz   = (const float*)d_in[0];
    const float* h1    = (const float*)d_in[1];
    const float* h2_in = (const float*)d_in[2];
    const float* dg_w1 = (const float*)d_in[3];
    const float* dg_b1 = (const float*)d_in[4];
    const float* dg_s1 = (const float*)d_in[5];
    const float* dg_t1 = (const float*)d_in[6];
    const float* dg_w2 = (const float*)d_in[7];
    const float* dg_b2 = (const float*)d_in[8];
    const float* dg_s2 = (const float*)d_in[9];
    const float* dg_t2 = (const float*)d_in[10];
    const float* dg_w3 = (const float*)d_in[11];
    const float* dg_b3 = (const float*)d_in[12];
    const float* dg_s3 = (const float*)d_in[13];
    const float* dg_t3 = (const float*)d_in[14];
    const float* ed_w1 = (const float*)d_in[15];
    const float* ed_b1 = (const float*)d_in[16];
    const float* ed_w2 = (const float*)d_in[17];
    const float* ed_b2 = (const float*)d_in[18];
    const float* w1 = (const float*)d_in[19];
    const float* b1 = (const float*)d_in[20];
    const float* s1 = (const float*)d_in[21];
    const float* t1 = (const float*)d_in[22];
    const float* w2 = (const float*)d_in[23];
    const float* b2 = (const float*)d_in[24];
    const float* s2 = (const float*)d_in[25];
    const float* t2 = (const float*)d_in[26];
    const float* w3 = (const float*)d_in[27];
    const float* b3 = (const float*)d_in[28];
    const float* s3 = (const float*)d_in[29];
    const float* t3 = (const float*)d_in[30];

    float* out = (float*)d_out;

    char* ws = (char*)d_ws;
    size_t off = 0;
    auto alloc = [&](size_t bytes) {
        char* p = ws + off;
        off += (bytes + 255) & ~(size_t)255;
        return p;
    };
    unsigned int* maxd2 = (unsigned int*)alloc(256);
    short* wb1  = (short*)alloc((size_t)256 * 1024 * 2);
    short* wb2  = (short*)alloc((size_t)64  * 256  * 2);
    short* wb3  = (short*)alloc((size_t)64  * 64   * 2);
    short* wbf1 = (short*)alloc((size_t)512 * 192  * 2);
    short* wbf2 = (short*)alloc((size_t)256 * 512  * 2);
    short* wbf3 = (short*)alloc((size_t)128 * 256  * 2);
    short* zinT = (short*)alloc((size_t)BATCH * N_PTS * 192 * 2);   // 6.3 MB
    short* bufA = (short*)alloc((size_t)BATCH * N_PTS * 256 * 2);   // 8.4 MB
    short* bufB = (short*)alloc((size_t)BATCH * N_PTS * 512 * 2);   // 16.8 MB
    short* bufC = (short*)alloc((size_t)BATCH * N_PTS * 64 * 2);    // 2.1 MB
    float* pbuf = (float*)alloc((size_t)BATCH * JS * N_PTS * 16 * 4); // 8.4 MB
    float* part = (float*)alloc((size_t)2 * BATCH * N_PTS * 256 * 4); // 33.5 MB
    short* bufD = bufA;   // [B][N][256] fp16 (F2 output; bufA otherwise unused)

    // all weight conversions + maxd2 init in one launch
    {
        WcArgs a;
        const float* Wp[6] = {dg_w1, dg_w2, dg_w3, w1, w2, w3};
        short* Op[6] = {wb1, wb2, wb3, wbf1, wbf2, wbf3};
        int Mv[6] = {256, 64, 32, 512, 256, 128};
        int Kv[6] = {1024, 256, 64, 164, 512, 256};
        int Mp[6] = {256, 64, 64, 512, 256, 128};
        int Kp[6] = {1024, 256, 64, 192, 512, 256};
        int acc0 = 0;
        for (int l = 0; l < 6; ++l) {
            a.W[l] = Wp[l]; a.O[l] = Op[l];
            a.M[l] = Mv[l]; a.K[l] = Kv[l]; a.Kp[l] = Kp[l];
            a.start[l] = acc0;
            acc0 += Mp[l] * Kp[l];
        }
        a.start[6] = acc0;
        a.maxd2 = maxd2;
        wconv_all_kernel<<<(acc0 + 255) / 256, 256, 0, stream>>>(a);
    }

    // eigen branch
    dim3 gsplit(N_PTS / 64, JS, BATCH);
    radius_max_kernel<<<gsplit, 256, 0, stream>>>(xyz, maxd2);
    eigen_accum_kernel<<<gsplit, 256, 0, stream>>>(xyz, maxd2, pbuf);
    eigen_finalize_kernel<<<(BATCH * N_PTS + 255) / 256, 256, 0, stream>>>(
        xyz, pbuf, ed_w1, ed_b1, ed_w2, ed_b2, zinT, out);

    h1_transpose_kernel<<<dim3(N_PTS / 32, BATCH), 256, 0, stream>>>(h1, zinT);

    // GEMM chain
    // DG1 split-K (raw f32 partials): 1024 -> 256
    dg1_splitk_kernel<<<dim3(N_PTS/64, 2, BATCH * 2), 256, 0, stream>>>(
        wb1, h2_in, part);
    // DG2 fused combine (partials + DG1 activation in staging): 256 -> 64
    dg2_fused_kernel<<<dim3(N_PTS/32, 1, BATCH), 256, 0, stream>>>(
        wb2, part, dg_b1, dg_s1, dg_t1, dg_b2, dg_s2, dg_t2, bufC);
    // DG3: 64 -> 32 (zinT ch 128..159)
    mfma_gemm<64, 32, true><<<dim3(N_PTS/32, 1, BATCH), 256, 0, stream>>>(
        wb3, bufC, dg_b3, dg_s3, dg_t3, zinT + 128, 32, 64, 192, 0);
    // F1: 192 -> 512
    mfma_gemm<128, 64, true><<<dim3(N_PTS/64, 4, BATCH), 256, 0, stream>>>(
        wbf1, zinT, b1, s1, t1, bufB, 512, 192, 512, 0);
    // F2: 512 -> 256
    mfma_gemm<64, 64, true><<<dim3(N_PTS/64, 4, BATCH), 256, 0, stream>>>(
        wbf2, bufB, b2, s2, t2, bufD, 256, 512, 256, 0);
    // F3: 256 -> 128 (f32 [b][m][n] into d_out after xyz)
    mfma_gemm<64, 32, false><<<dim3(N_PTS/32, 2, BATCH), 256, 0, stream>>>(
        wbf3, bufD, b3, s3, t3, out + (size_t)BATCH * N_PTS * 3, 128, 256, 0,
        (size_t)128 * N_PTS);
}